// Round 1
// 3131.445 us; speedup vs baseline: 1.2339x; 1.2339x over previous
//
#include <hip/hip_runtime.h>

typedef __bf16 bf8 __attribute__((ext_vector_type(8)));
typedef float  f4  __attribute__((ext_vector_type(4)));
typedef unsigned long long uptr;

__device__ __forceinline__ void gload16(const void* g, void* l){
  __builtin_amdgcn_global_load_lds(
      (const __attribute__((address_space(1))) unsigned int*)(uptr)g,
      (__attribute__((address_space(3))) unsigned int*)(uptr)l,
      16, 0, 0);
}

// ---------------- pillar stage ----------------

__global__ __launch_bounds__(256) void k_cell(const float* __restrict__ x, int* __restrict__ cellArr,
                                              float* __restrict__ cnt, float* __restrict__ cent){
  int p = blockIdx.x*256 + threadIdx.x;            // 65536 points
  float x0 = x[p*3+0], x1 = x[p*3+1], x2 = x[p*3+2];
  float y0 = fminf(fmaxf(x0 + 1.0f, 0.0f), 1.99f);
  float y1 = fminf(fmaxf(x2 + 1.0f, 0.0f), 1.99f);
  int i0 = (int)floorf(y0 / 0.2f);
  int i1 = (int)floorf(y1 / 0.2f);
  int b = p >> 11;
  int cell = b*100 + i0*10 + i1;
  cellArr[p] = cell;
  atomicAdd(&cnt[cell], 1.0f);
  atomicAdd(&cent[cell*3+0], x1);
  atomicAdd(&cent[cell*3+1], x0);
  atomicAdd(&cent[cell*3+2], x2);
}

__global__ void k_centdiv(float* cent, const float* cnt){
  int i = blockIdx.x*256 + threadIdx.x;
  if (i < 3200*3) cent[i] /= fmaxf(cnt[i/3], 1.0f);
}

// counting-sort scan: base = exclusive prefix of cnt; wptr = copy of base
__global__ __launch_bounds__(256) void k_scan(const float* __restrict__ cnt,
                                              int* __restrict__ base, int* __restrict__ wptr){
  __shared__ int a[256];
  int tid = threadIdx.x;
  int start = tid*13, end = start+13; if (end > 3200) end = 3200;
  int local = 0;
  for (int i = start; i < end; i++) local += (int)cnt[i];
  a[tid] = local;
  __syncthreads();
  for (int off = 1; off < 256; off <<= 1){
    int t = (tid >= off) ? a[tid - off] : 0;
    __syncthreads();
    a[tid] += t;
    __syncthreads();
  }
  int run = a[tid] - local;
  for (int i = start; i < end; i++){
    base[i] = run; wptr[i] = run;
    run += (int)cnt[i];
  }
}

__global__ __launch_bounds__(256) void k_scatter(const int* __restrict__ cellArr,
                                                 int* __restrict__ wptr, int* __restrict__ order){
  int p = blockIdx.x*256 + threadIdx.x;
  int c = cellArr[p];
  int pos = atomicAdd(&wptr[c], 1);
  order[pos] = p;
}

__global__ __launch_bounds__(256) void k_pointmlp(const float* __restrict__ x,
    const float* __restrict__ W1, const float* __restrict__ W2, const float* __restrict__ W3,
    const float* __restrict__ cent, const int* __restrict__ cellArr,
    const int* __restrict__ order, int* __restrict__ cellSlot, __bf16* __restrict__ A2){
  __shared__ float w1s[6*32];
  __shared__ float w2s[32*64];
  __shared__ float w3s[64*128];
  int tid = threadIdx.x;
  for (int i = tid; i < 192;  i += 256) w1s[i] = W1[i];
  for (int i = tid; i < 2048; i += 256) w2s[i] = W2[i];
  for (int i = tid; i < 8192; i += 256) w3s[i] = W3[i];
  __syncthreads();
  int s = blockIdx.x*256 + tid;                 // sorted slot
  int p = order[s];
  int cell = cellArr[p];
  cellSlot[s] = cell;
  float pf0 = x[p*3+1], pf1 = x[p*3+0], pf2 = x[p*3+2];
  float a[6] = {pf0, pf1, pf2, pf0 - cent[cell*3+0], pf1 - cent[cell*3+1], pf2 - cent[cell*3+2]};
  float h1[32];
  #pragma unroll
  for (int f = 0; f < 32; f++){
    float t = 0.f;
    #pragma unroll
    for (int i = 0; i < 6; i++) t += a[i]*w1s[i*32+f];
    h1[f] = fmaxf(t, 0.f);
  }
  float h2[64];
  #pragma unroll
  for (int f = 0; f < 64; f++){
    float t = 0.f;
    #pragma unroll
    for (int i = 0; i < 32; i++) t += h1[i]*w2s[i*64+f];
    h2[f] = fmaxf(t, 0.f);
  }
  for (int f0 = 0; f0 < 128; f0 += 8){
    __bf16 tmp[8];
    #pragma unroll
    for (int j = 0; j < 8; j++){
      float t = 0.f;
      #pragma unroll
      for (int i = 0; i < 64; i++) t += h2[i]*w3s[i*128+f0+j];
      tmp[j] = (__bf16)fmaxf(t, 0.f);
    }
    *reinterpret_cast<uint4*>(&A2[(size_t)s*256 + f0]) = *reinterpret_cast<uint4*>(tmp);
  }
}

__global__ __launch_bounds__(128) void k_poolh(const __bf16* __restrict__ A2,
    const int* __restrict__ base, const float* __restrict__ cnt, float* __restrict__ pooled){
  int c = blockIdx.x, f = threadIdx.x;
  int b0 = base[c], n = (int)cnt[c];
  float v = 0.f;
  for (int k = 0; k < n; k++) v = fmaxf(v, (float)A2[(size_t)(b0+k)*256 + f]);
  pooled[c*128 + f] = v;
}

__global__ __launch_bounds__(256) void k_fill(const float* __restrict__ pooled,
    const int* __restrict__ cellSlot, __bf16* __restrict__ A2){
  int idx = blockIdx.x*256 + threadIdx.x;       // 65536*128
  int s = idx >> 7, f = idx & 127;
  A2[(size_t)s*256 + 128 + f] = (__bf16)pooled[cellSlot[s]*128 + f];
}

__global__ __launch_bounds__(256) void k_pillarpool(const __bf16* __restrict__ h2c,
    const int* __restrict__ base, const float* __restrict__ cnt, float* __restrict__ pillar, int cs){
  int c = blockIdx.x, tid = threadIdx.x;
  int b0 = base[c], e0 = b0 + (int)cnt[c];
  int lo = b0 > cs ? b0 : cs;
  int hi = e0 < cs + 16384 ? e0 : cs + 16384;
  if (lo >= hi) return;
  for (int f = tid; f < 768; f += 256){
    float v = 0.f;
    for (int s = lo; s < hi; s++) v = fmaxf(v, (float)h2c[(size_t)(s - cs)*768 + f]);
    atomicMax((int*)&pillar[(size_t)c*768 + f], __float_as_int(v));
  }
}

__global__ void k_assemble(const float* __restrict__ pillar,
    const float* __restrict__ bn_g, const float* __restrict__ bn_b,
    const float* __restrict__ bn_mean, const float* __restrict__ bn_var,
    const float* __restrict__ cls_t, const float* __restrict__ pos,
    float* __restrict__ tokens){
  int idx = blockIdx.x*256 + threadIdx.x;          // 3232*768
  int m = idx / 768, d = idx % 768;
  int b = m / 101, t = m % 101;
  float v;
  if (t == 0) v = cls_t[d];
  else {
    int s = t - 1;
    float pv = pillar[((size_t)b*100 + s)*768 + d];
    float inv = bn_g[s]*rsqrtf(bn_var[s] + 1e-5f);
    v = (pv - bn_mean[s])*inv + bn_b[s];
  }
  tokens[idx] = v + pos[t*768 + d];
}

// ---------------- weight transpose-convert ----------------

__global__ __launch_bounds__(256) void k_transpose(const float* __restrict__ W, __bf16* __restrict__ Wt,
                                                   int K, int N){
  __shared__ float t[32][33];
  int n0 = blockIdx.x*32, k0 = blockIdx.y*32;
  int tx = threadIdx.x & 31, ty = threadIdx.x >> 5;
  #pragma unroll
  for (int i = 0; i < 32; i += 8){
    int k = k0 + ty + i, n = n0 + tx;
    t[ty+i][tx] = (k < K && n < N) ? W[(size_t)k*N + n] : 0.f;
  }
  __syncthreads();
  #pragma unroll
  for (int i = 0; i < 32; i += 8){
    int n = n0 + ty + i, k = k0 + tx;
    if (n < N && k < K) Wt[(size_t)n*K + k] = (__bf16)t[tx][ty+i];
  }
}

__global__ __launch_bounds__(256) void k_transpose_all(
    const float* __restrict__ qw, const float* __restrict__ pw,
    const float* __restrict__ f1, const float* __restrict__ f2,
    __bf16* __restrict__ wq, __bf16* __restrict__ wp,
    __bf16* __restrict__ w1, __bf16* __restrict__ w2){
  int id = blockIdx.x;
  const float* W; __bf16* Wt; int K, N, nx, ny;
  if (id < 1728){ W=qw; Wt=wq; K=768;  N=2304; nx=id%72; ny=id/72; }
  else if (id < 2304){ id-=1728; W=pw; Wt=wp; K=768;  N=768;  nx=id%24; ny=id/24; }
  else if (id < 4608){ id-=2304; W=f1; Wt=w1; K=768;  N=3072; nx=id%96; ny=id/96; }
  else {               id-=4608; W=f2; Wt=w2; K=3072; N=768;  nx=id%24; ny=id/24; }
  __shared__ float t[32][33];
  int n0 = nx*32, k0 = ny*32;
  int tx = threadIdx.x & 31, ty = threadIdx.x >> 5;
  #pragma unroll
  for (int i = 0; i < 32; i += 8) t[ty+i][tx] = W[(size_t)(k0+ty+i)*N + n0+tx];
  __syncthreads();
  #pragma unroll
  for (int i = 0; i < 32; i += 8) Wt[(size_t)(n0+ty+i)*K + k0+tx] = (__bf16)t[tx][ty+i];
}

// ---------------- bf16 MFMA GEMM (m97-style global_load_lds staging) ----------------
// C[M][N] = A[M][K] @ Bt[N][K]^T ; act: 0 none, 1 relu, 2 gelu(exact)
// splitK > 1: grid.z = splitK, fp32 atomicAdd into outF (which pre-holds the
// residual); bias added by the z==0 split only; act must be 0.

__global__ __launch_bounds__(256) void k_gemm(const __bf16* __restrict__ A, const __bf16* __restrict__ Bt,
    const float* __restrict__ bias, const float* __restrict__ res,
    float* __restrict__ outF, __bf16* __restrict__ outB,
    int M, int N, int K, int act, int splitK){
  __shared__ alignas(16) __bf16 As[128*32];
  __shared__ alignas(16) __bf16 Bs[128*32];
  int tid  = threadIdx.x;
  int m0 = blockIdx.y*128, n0 = blockIdx.x*128;
  int z = blockIdx.z;
  int kLen = K / splitK, k0 = z*kLen;
  int wave = tid >> 6, lane = tid & 63;
  int wm = (wave >> 1)*64, wn = (wave & 1)*64;
  int r16 = lane & 15, q = lane >> 4;
  int lrow = lane >> 2, lpc = lane & 3;
  f4 acc[4][4];
  #pragma unroll
  for (int i = 0; i < 4; i++)
    #pragma unroll
    for (int j = 0; j < 4; j++) acc[i][j] = (f4){0.f,0.f,0.f,0.f};

  for (int kt = k0; kt < k0 + kLen; kt += 32){
    #pragma unroll
    for (int s = 0; s < 2; s++){
      int rg  = wave*2 + s;
      int row = rg*16 + lrow;
      int gm = m0 + row; if (gm >= M) gm = M - 1;
      gload16(A  + (size_t)gm*K + kt + lpc*8, (char*)As + rg*1024 + lane*16);
      int gn = n0 + row;
      gload16(Bt + (size_t)gn*K + kt + lpc*8, (char*)Bs + rg*1024 + lane*16);
    }
    __syncthreads();
    bf8 af[4], bq[4];
    #pragma unroll
    for (int i = 0; i < 4; i++) af[i] = *reinterpret_cast<const bf8*>(&As[(wm + i*16 + r16)*32 + q*8]);
    #pragma unroll
    for (int j = 0; j < 4; j++) bq[j] = *reinterpret_cast<const bf8*>(&Bs[(wn + j*16 + r16)*32 + q*8]);
    #pragma unroll
    for (int i = 0; i < 4; i++)
      #pragma unroll
      for (int j = 0; j < 4; j++)
        acc[i][j] = __builtin_amdgcn_mfma_f32_16x16x32_bf16(af[i], bq[j], acc[i][j], 0, 0, 0);
    __syncthreads();
  }

  #pragma unroll
  for (int i = 0; i < 4; i++){
    #pragma unroll
    for (int j = 0; j < 4; j++){
      int nn = n0 + wn + j*16 + r16;
      float bv = (bias && z == 0) ? bias[nn] : 0.f;
      #pragma unroll
      for (int r = 0; r < 4; r++){
        int m = m0 + wm + i*16 + q*4 + r;
        if (m >= M) continue;
        float v = acc[i][j][r] + bv;
        if (splitK > 1){
          atomicAdd(&outF[(size_t)m*N + nn], v);
        } else {
          if (act == 1) v = fmaxf(v, 0.f);
          else if (act == 2) v = 0.5f*v*(1.f + erff(v*0.70710678118654752f));
          if (outB){
            outB[(size_t)m*N + nn] = (__bf16)v;
          } else {
            float rv = res ? res[(size_t)m*N + nn] : 0.f;
            outF[(size_t)m*N + nn] = rv + v;
          }
        }
      }
    }
  }
}

// ---------------- layernorm (row = 768) ----------------

__global__ __launch_bounds__(256) void k_ln(const float* __restrict__ in, const float* __restrict__ g,
    const float* __restrict__ bta, __bf16* __restrict__ outB, float* __restrict__ outF, int rowMul){
  int orow = blockIdx.x;
  const float* xr = in + (size_t)orow*rowMul*768;
  int tid = threadIdx.x;
  float v0 = xr[tid], v1 = xr[tid+256], v2 = xr[tid+512];
  float s = v0+v1+v2, s2 = v0*v0 + v1*v1 + v2*v2;
  #pragma unroll
  for (int off = 32; off > 0; off >>= 1){ s += __shfl_xor(s, off); s2 += __shfl_xor(s2, off); }
  __shared__ float rs[4], rq[4];
  int w = tid >> 6;
  if ((tid & 63) == 0){ rs[w] = s; rq[w] = s2; }
  __syncthreads();
  s = rs[0]+rs[1]+rs[2]+rs[3]; s2 = rq[0]+rq[1]+rq[2]+rq[3];
  float mean = s*(1.f/768.f);
  float var  = s2*(1.f/768.f) - mean*mean;
  float rstd = rsqrtf(var + 1e-5f);
  size_t ob = (size_t)orow*768;
  float y0 = (v0-mean)*rstd*g[tid]     + bta[tid];
  float y1 = (v1-mean)*rstd*g[tid+256] + bta[tid+256];
  float y2 = (v2-mean)*rstd*g[tid+512] + bta[tid+512];
  if (outB){ outB[ob+tid]=(__bf16)y0; outB[ob+tid+256]=(__bf16)y1; outB[ob+tid+512]=(__bf16)y2; }
  else     { outF[ob+tid]=y0;         outF[ob+tid+256]=y1;         outF[ob+tid+512]=y2; }
}

// ---------------- MFMA attention: one block per (b,h), T=101, HD=64 ----------------
// Q,K fragments loaded direct global->register (fragment layout == contiguous 16B).
// V staged transposed in LDS (Vt[d][t]) so PV B-fragment is one ds_read_b128.
// 8 row-tiles (128 rows, pad>=101 discarded) over 4 waves x 2 static rt:
// all accumulator indexing is compile-time -> registers, no scratch.

#define PSS 136   // Ps row stride (elements): 272B, 16B-aligned
#define VTS 136   // Vt row stride (elements): 272B, 16B-aligned

__global__ __launch_bounds__(256) void k_attn(const __bf16* __restrict__ qkvB, __bf16* __restrict__ o){
  __shared__ alignas(16) __bf16 smem[64*VTS + 128*PSS];
  __bf16* Vt = smem;             // [64][VTS] : Vt[d][t]
  __bf16* Ps = smem + 64*VTS;    // [128][PSS]
  int b = blockIdx.x / 12, h = blockIdx.x % 12;
  int tid = threadIdx.x;
  const __bf16* basep = qkvB + (size_t)(b*101)*2304 + h*64;

  // stage V transposed: 16B coalesced global loads, bank-staggered scalar LDS writes
  #pragma unroll
  for (int it = 0; it < 4; it++){
    int c = tid + it*256;          // [0,1024): 128 t-rows x 8 d-chunks
    int t = c >> 3, d0 = c & 7;
    bf8 v;
    if (t < 101){
      v = *reinterpret_cast<const bf8*>(&basep[(size_t)t*2304 + 1536 + d0*8]);
    } else {
      #pragma unroll
      for (int j = 0; j < 8; j++) v[j] = (__bf16)0.f;
    }
    #pragma unroll
    for (int j = 0; j < 8; j++){
      int jj = (j + d0) & 7;       // stagger banks across the 8-lane same-t group
      Vt[(d0*8 + jj)*VTS + t] = v[jj];
    }
  }

  int wave = tid >> 6, lane = tid & 63;
  int r16 = lane & 15, q = lane >> 4;

  // QK^T: direct global fragment loads, no LDS, no barrier
  f4 sacc[2][7];
  #pragma unroll
  for (int rt = 0; rt < 2; rt++)
    #pragma unroll
    for (int j = 0; j < 7; j++) sacc[rt][j] = (f4){0.f,0.f,0.f,0.f};
  #pragma unroll
  for (int kt = 0; kt < 64; kt += 32){
    bf8 aq[2];
    #pragma unroll
    for (int rt = 0; rt < 2; rt++){
      int row = (wave + rt*4)*16 + r16; if (row > 100) row = 100;
      aq[rt] = *reinterpret_cast<const bf8*>(&basep[(size_t)row*2304 + kt + q*8]);
    }
    #pragma unroll
    for (int j = 0; j < 7; j++){
      int krow = j*16 + r16; if (krow > 100) krow = 100;
      bf8 kf = *reinterpret_cast<const bf8*>(&basep[(size_t)krow*2304 + 768 + kt + q*8]);
      #pragma unroll
      for (int rt = 0; rt < 2; rt++)
        sacc[rt][j] = __builtin_amdgcn_mfma_f32_16x16x32_bf16(aq[rt], kf, sacc[rt][j], 0, 0, 0);
    }
  }

  // softmax (per row over 7 j-regs x 16 lanes) + write P to LDS
  #pragma unroll
  for (int rt = 0; rt < 2; rt++){
    int m0 = (wave + rt*4)*16;
    #pragma unroll
    for (int r = 0; r < 4; r++){
      float s[7];
      #pragma unroll
      for (int j = 0; j < 7; j++){
        s[j] = sacc[rt][j][r] * 0.125f;
        if (j == 6 && r16 >= 5) s[j] = -1e30f;
      }
      float mx = s[0];
      #pragma unroll
      for (int j = 1; j < 7; j++) mx = fmaxf(mx, s[j]);
      #pragma unroll
      for (int off2 = 1; off2 < 16; off2 <<= 1) mx = fmaxf(mx, __shfl_xor(mx, off2));
      float p[7], sum = 0.f;
      #pragma unroll
      for (int j = 0; j < 7; j++){ p[j] = __expf(s[j] - mx); sum += p[j]; }
      #pragma unroll
      for (int off2 = 1; off2 < 16; off2 <<= 1) sum += __shfl_xor(sum, off2);
      float inv = 1.f / sum;
      int row = m0 + q*4 + r;
      #pragma unroll
      for (int j = 0; j < 7; j++) Ps[row*PSS + j*16 + r16] = (__bf16)(p[j]*inv);
      Ps[row*PSS + 112 + r16] = (__bf16)0.f;
    }
  }
  __syncthreads();

  // PV: A from Ps, B from Vt — both single ds_read_b128 per fragment
  f4 oacc[2][4];
  #pragma unroll
  for (int rt = 0; rt < 2; rt++)
    #pragma unroll
    for (int n = 0; n < 4; n++) oacc[rt][n] = (f4){0.f,0.f,0.f,0.f};
  #pragma unroll
  for (int kt = 0; kt < 128; kt += 32){
    bf8 af[2];
    #pragma unroll
    for (int rt = 0; rt < 2; rt++)
      af[rt] = *reinterpret_cast<const bf8*>(&Ps[((wave + rt*4)*16 + r16)*PSS + kt + q*8]);
    #pragma unroll
    for (int n = 0; n < 4; n++){
      bf8 bq = *reinterpret_cast<const bf8*>(&Vt[(n*16 + r16)*VTS + kt + q*8]);
      #pragma unroll
      for (int rt = 0; rt < 2; rt++)
        oacc[rt][n] = __builtin_amdgcn_mfma_f32_16x16x32_bf16(af[rt], bq, oacc[rt][n], 0, 0, 0);
    }
  }

  #pragma unroll
  for (int rt = 0; rt < 2; rt++){
    int m0 = (wave + rt*4)*16;
    #pragma unroll
    for (int n = 0; n < 4; n++){
      #pragma unroll
      for (int r = 0; r < 4; r++){
        int t = m0 + q*4 + r;
        if (t < 101)
          o[((size_t)(b*101 + t))*768 + h*64 + n*16 + r16] = (__bf16)oacc[rt][n][r];
      }
    }
  }
}

__global__ void k_head(const float* __restrict__ cls, const float* __restrict__ hw,
                       const float* __restrict__ hb, float* __restrict__ out){
  int b = blockIdx.x, c = threadIdx.x;
  if (c < 40){
    float s = hb[c];
    for (int k = 0; k < 768; k++) s += cls[b*768 + k]*hw[k*40 + c];
    out[b*40 + c] = s;
  }
}

// ---------------- launch ----------------

extern "C" void kernel_launch(void* const* d_in, const int* in_sizes, int n_in,
                              void* d_out, int out_size, void* d_ws, size_t ws_size,
                              hipStream_t stream){
  const float* x       = (const float*)d_in[0];
  const float* W1      = (const float*)d_in[1];
  const float* W2      = (const float*)d_in[2];
  const float* W3      = (const float*)d_in[3];
  const float* Wa      = (const float*)d_in[4];
  const float* bn_g    = (const float*)d_in[5];
  const float* bn_b    = (const float*)d_in[6];
  const float* bn_mean = (const float*)d_in[7];
  const float* bn_var  = (const float*)d_in[8];
  const float* cls_t   = (const float*)d_in[9];
  const float* pos     = (const float*)d_in[10];
  const float* ln1_g   = (const float*)d_in[11];
  const float* ln1_b   = (const float*)d_in[12];
  const float* qkv_w   = (const float*)d_in[13];
  const float* proj_w  = (const float*)d_in[14];
  const float* proj_b  = (const float*)d_in[15];
  const float* ln2_g   = (const float*)d_in[16];
  const float* ln2_b   = (const float*)d_in[17];
  const float* fc1_w   = (const float*)d_in[18];
  const float* fc1_b   = (const float*)d_in[19];
  const float* fc2_w   = (const float*)d_in[20];
  const float* fc2_b   = (const float*)d_in[21];
  const float* norm_g  = (const float*)d_in[22];
  const float* norm_b  = (const float*)d_in[23];
  const float* head_w  = (const float*)d_in[24];
  const float* head_b  = (const float*)d_in[25];

  char* ws = (char*)d_ws;
  size_t off = 0;
  auto alloc = [&](size_t bytes)->void*{ void* p = ws + off; off += (bytes + 255) & ~(size_t)255; return p; };
  // --- persistent region ---
  float* cnt     = (float*)alloc(3200*4);
  float* cent    = (float*)alloc(3200*3*4);
  float* pillar  = (float*)alloc((size_t)3200*768*4);
  size_t zbytes  = (size_t)((char*)pillar - (char*)cnt) + (size_t)3200*768*4;
  int*   base    = (int*)  alloc(3200*4);
  int*   wptr    = (int*)  alloc(3200*4);
  int*   order   = (int*)  alloc((size_t)65536*4);
  int*   cellSlot= (int*)  alloc((size_t)65536*4);
  int*   cellArr = (int*)  alloc((size_t)65536*4);
  float* pooled  = (float*)alloc((size_t)3200*128*4);
  float* tokens  = (float*)alloc((size_t)3232*768*4);
  float* cls     = (float*)alloc((size_t)32*768*4);
  __bf16* wWa    = (__bf16*)alloc((size_t)768*256*2);
  // --- overlaid region R ---
  size_t offR = off;
  __bf16* A2  = (__bf16*)alloc((size_t)65536*256*2);
  __bf16* h2c = (__bf16*)alloc((size_t)16384*768*2);
  size_t endPillarPhase = off;
  off = offR;
  __bf16* y    = (__bf16*)alloc((size_t)3232*768*2);
  __bf16* qkvB = (__bf16*)alloc((size_t)3232*2304*2);
  __bf16* o    = (__bf16*)alloc((size_t)3232*768*2);
  __bf16* mlp  = (__bf16*)alloc((size_t)3232*3072*2);
  __bf16* wq   = (__bf16*)alloc((size_t)768*2304*2);
  __bf16* wp   = (__bf16*)alloc((size_t)768*768*2);
  __bf16* w1   = (__bf16*)alloc((size_t)768*3072*2);
  __bf16* w2   = (__bf16*)alloc((size_t)3072*768*2);
  if (off < endPillarPhase) off = endPillarPhase;
  (void)ws_size; (void)in_sizes; (void)n_in; (void)out_size;

  hipMemsetAsync(cnt, 0, zbytes, stream);

  // pillar feature stage
  k_cell<<<256,256,0,stream>>>(x, cellArr, cnt, cent);
  k_centdiv<<<38,256,0,stream>>>(cent, cnt);
  k_scan<<<1,256,0,stream>>>(cnt, base, wptr);
  k_scatter<<<256,256,0,stream>>>(cellArr, wptr, order);
  k_pointmlp<<<256,256,0,stream>>>(x, W1, W2, W3, cent, cellArr, order, cellSlot, A2);
  k_poolh<<<3200,128,0,stream>>>(A2, base, cnt, pooled);
  k_fill<<<32768,256,0,stream>>>(pooled, cellSlot, A2);
  k_transpose<<<dim3(24,8),256,0,stream>>>(Wa, wWa, 256, 768);
  for (int c = 0; c < 4; c++){
    k_gemm<<<dim3(6,128),256,0,stream>>>(A2 + (size_t)c*16384*256, wWa, nullptr, nullptr,
                                         nullptr, h2c, 16384, 768, 256, 1, 1);
    k_pillarpool<<<3200,256,0,stream>>>(h2c, base, cnt, pillar, c*16384);
  }
  k_assemble<<<9696,256,0,stream>>>(pillar, bn_g, bn_b, bn_mean, bn_var, cls_t, pos, tokens);

  // transformer
  for (int l = 0; l < 12; l++){
    k_transpose_all<<<6912,256,0,stream>>>(qkv_w + (size_t)l*768*2304, proj_w + (size_t)l*768*768,
                                           fc1_w + (size_t)l*768*3072, fc2_w + (size_t)l*3072*768,
                                           wq, wp, w1, w2);
    k_ln<<<3232,256,0,stream>>>(tokens, ln1_g + l*768, ln1_b + l*768, y, nullptr, 1);
    k_gemm<<<dim3(18,26),256,0,stream>>>(y, wq, nullptr, nullptr, nullptr, qkvB, 3232, 2304, 768, 0, 1);
    k_attn<<<384,256,0,stream>>>(qkvB, o);
    // proj: split-K=4, atomic += into tokens (tokens already holds residual h)
    k_gemm<<<dim3(6,26,4),256,0,stream>>>(o, wp, proj_b + l*768, nullptr, tokens, nullptr,
                                          3232, 768, 768, 0, 4);
    k_ln<<<3232,256,0,stream>>>(tokens, ln2_g + l*768, ln2_b + l*768, y, nullptr, 1);
    k_gemm<<<dim3(24,26),256,0,stream>>>(y, w1, fc1_b + l*3072, nullptr, nullptr, mlp, 3232, 3072, 768, 2, 1);
    // fc2: split-K=4, atomic += into tokens
    k_gemm<<<dim3(6,26,4),256,0,stream>>>(mlp, w2, fc2_b + l*768, nullptr, tokens, nullptr,
                                          3232, 768, 3072, 0, 4);
  }

  k_ln<<<32,256,0,stream>>>(tokens, norm_g, norm_b, nullptr, cls, 101);
  k_head<<<32,64,0,stream>>>(cls, head_w, head_b, (float*)d_out);
}

// Round 2
// 2906.208 us; speedup vs baseline: 1.3295x; 1.0775x over previous
//
#include <hip/hip_runtime.h>

typedef __bf16 bf8 __attribute__((ext_vector_type(8)));
typedef float  f4  __attribute__((ext_vector_type(4)));
typedef unsigned long long uptr;

__device__ __forceinline__ void gload16(const void* g, void* l){
  __builtin_amdgcn_global_load_lds(
      (const __attribute__((address_space(1))) unsigned int*)(uptr)g,
      (__attribute__((address_space(3))) unsigned int*)(uptr)l,
      16, 0, 0);
}

// ---------------- pillar stage ----------------

__global__ __launch_bounds__(256) void k_cell(const float* __restrict__ x, int* __restrict__ cellArr,
                                              float* __restrict__ cnt, float* __restrict__ cent){
  int p = blockIdx.x*256 + threadIdx.x;            // 65536 points
  float x0 = x[p*3+0], x1 = x[p*3+1], x2 = x[p*3+2];
  float y0 = fminf(fmaxf(x0 + 1.0f, 0.0f), 1.99f);
  float y1 = fminf(fmaxf(x2 + 1.0f, 0.0f), 1.99f);
  int i0 = (int)floorf(y0 / 0.2f);
  int i1 = (int)floorf(y1 / 0.2f);
  int b = p >> 11;
  int cell = b*100 + i0*10 + i1;
  cellArr[p] = cell;
  atomicAdd(&cnt[cell], 1.0f);
  atomicAdd(&cent[cell*3+0], x1);
  atomicAdd(&cent[cell*3+1], x0);
  atomicAdd(&cent[cell*3+2], x2);
}

// counting-sort scan: base = exclusive prefix of cnt; wptr = copy of base
__global__ __launch_bounds__(256) void k_scan(const float* __restrict__ cnt,
                                              int* __restrict__ base, int* __restrict__ wptr){
  __shared__ int a[256];
  int tid = threadIdx.x;
  int start = tid*13, end = start+13; if (end > 3200) end = 3200;
  int local = 0;
  for (int i = start; i < end; i++) local += (int)cnt[i];
  a[tid] = local;
  __syncthreads();
  for (int off = 1; off < 256; off <<= 1){
    int t = (tid >= off) ? a[tid - off] : 0;
    __syncthreads();
    a[tid] += t;
    __syncthreads();
  }
  int run = a[tid] - local;
  for (int i = start; i < end; i++){
    base[i] = run; wptr[i] = run;
    run += (int)cnt[i];
  }
}

__global__ __launch_bounds__(256) void k_scatter(const int* __restrict__ cellArr,
                                                 int* __restrict__ wptr, int* __restrict__ order){
  int p = blockIdx.x*256 + threadIdx.x;
  int c = cellArr[p];
  int pos = atomicAdd(&wptr[c], 1);
  order[pos] = p;
}

__global__ __launch_bounds__(256) void k_pointmlp(const float* __restrict__ x,
    const float* __restrict__ W1, const float* __restrict__ W2, const float* __restrict__ W3,
    const float* __restrict__ cent, const float* __restrict__ cnt, const int* __restrict__ cellArr,
    const int* __restrict__ order, int* __restrict__ cellSlot, __bf16* __restrict__ A2){
  __shared__ float w1s[6*32];
  __shared__ float w2s[32*64];
  __shared__ float w3s[64*128];
  int tid = threadIdx.x;
  for (int i = tid; i < 192;  i += 256) w1s[i] = W1[i];
  for (int i = tid; i < 2048; i += 256) w2s[i] = W2[i];
  for (int i = tid; i < 8192; i += 256) w3s[i] = W3[i];
  __syncthreads();
  int s = blockIdx.x*256 + tid;                 // sorted slot
  int p = order[s];
  int cell = cellArr[p];
  cellSlot[s] = cell;
  float pf0 = x[p*3+1], pf1 = x[p*3+0], pf2 = x[p*3+2];
  float cc = fmaxf(cnt[cell], 1.0f);
  float a[6] = {pf0, pf1, pf2,
                pf0 - cent[cell*3+0]/cc, pf1 - cent[cell*3+1]/cc, pf2 - cent[cell*3+2]/cc};
  float h1[32];
  #pragma unroll
  for (int f = 0; f < 32; f++){
    float t = 0.f;
    #pragma unroll
    for (int i = 0; i < 6; i++) t += a[i]*w1s[i*32+f];
    h1[f] = fmaxf(t, 0.f);
  }
  float h2[64];
  #pragma unroll
  for (int f = 0; f < 64; f++){
    float t = 0.f;
    #pragma unroll
    for (int i = 0; i < 32; i++) t += h1[i]*w2s[i*64+f];
    h2[f] = fmaxf(t, 0.f);
  }
  for (int f0 = 0; f0 < 128; f0 += 8){
    __bf16 tmp[8];
    #pragma unroll
    for (int j = 0; j < 8; j++){
      float t = 0.f;
      #pragma unroll
      for (int i = 0; i < 64; i++) t += h2[i]*w3s[i*128+f0+j];
      tmp[j] = (__bf16)fmaxf(t, 0.f);
    }
    *reinterpret_cast<uint4*>(&A2[(size_t)s*256 + f0]) = *reinterpret_cast<uint4*>(tmp);
  }
}

__global__ __launch_bounds__(128) void k_poolh(const __bf16* __restrict__ A2,
    const int* __restrict__ base, const float* __restrict__ cnt, float* __restrict__ pooled){
  int c = blockIdx.x, f = threadIdx.x;
  int b0 = base[c], n = (int)cnt[c];
  float v = 0.f;
  for (int k = 0; k < n; k++) v = fmaxf(v, (float)A2[(size_t)(b0+k)*256 + f]);
  pooled[c*128 + f] = v;
}

__global__ __launch_bounds__(256) void k_fill(const float* __restrict__ pooled,
    const int* __restrict__ cellSlot, __bf16* __restrict__ A2){
  int idx = blockIdx.x*256 + threadIdx.x;       // 65536*16
  int s = idx >> 4, f0 = (idx & 15) << 3;
  int cell = cellSlot[s];
  const float* pp = &pooled[cell*128 + f0];
  __bf16 tmp[8];
  #pragma unroll
  for (int j = 0; j < 8; j++) tmp[j] = (__bf16)pp[j];
  *reinterpret_cast<uint4*>(&A2[(size_t)s*256 + 128 + f0]) = *reinterpret_cast<uint4*>(tmp);
}

__global__ __launch_bounds__(256) void k_pillarpool(const __bf16* __restrict__ h2c,
    const int* __restrict__ base, const float* __restrict__ cnt, float* __restrict__ pillar, int cs){
  int c = blockIdx.x, tid = threadIdx.x;
  int b0 = base[c], e0 = b0 + (int)cnt[c];
  int lo = b0 > cs ? b0 : cs;
  int hi = e0 < cs + 16384 ? e0 : cs + 16384;
  if (lo >= hi) return;
  for (int f = tid; f < 768; f += 256){
    float v = 0.f;
    for (int s = lo; s < hi; s++) v = fmaxf(v, (float)h2c[(size_t)(s - cs)*768 + f]);
    atomicMax((int*)&pillar[(size_t)c*768 + f], __float_as_int(v));
  }
}

__global__ void k_assemble(const float* __restrict__ pillar,
    const float* __restrict__ bn_g, const float* __restrict__ bn_b,
    const float* __restrict__ bn_mean, const float* __restrict__ bn_var,
    const float* __restrict__ cls_t, const float* __restrict__ pos,
    float* __restrict__ tokens){
  int idx = blockIdx.x*256 + threadIdx.x;          // 3232*768
  int m = idx / 768, d = idx % 768;
  int b = m / 101, t = m % 101;
  float v;
  if (t == 0) v = cls_t[d];
  else {
    int s = t - 1;
    float pv = pillar[((size_t)b*100 + s)*768 + d];
    float inv = bn_g[s]*rsqrtf(bn_var[s] + 1e-5f);
    v = (pv - bn_mean[s])*inv + bn_b[s];
  }
  tokens[idx] = v + pos[t*768 + d];
}

// ---------------- weight transpose-convert ----------------

__global__ __launch_bounds__(256) void k_transpose(const float* __restrict__ W, __bf16* __restrict__ Wt,
                                                   int K, int N){
  __shared__ float t[32][33];
  int n0 = blockIdx.x*32, k0 = blockIdx.y*32;
  int tx = threadIdx.x & 31, ty = threadIdx.x >> 5;
  #pragma unroll
  for (int i = 0; i < 32; i += 8){
    int k = k0 + ty + i, n = n0 + tx;
    t[ty+i][tx] = (k < K && n < N) ? W[(size_t)k*N + n] : 0.f;
  }
  __syncthreads();
  #pragma unroll
  for (int i = 0; i < 32; i += 8){
    int n = n0 + ty + i, k = k0 + tx;
    if (n < N && k < K) Wt[(size_t)n*K + k] = (__bf16)t[tx][ty+i];
  }
}

// all 12 layers in one dispatch: grid (6912, 12)
__global__ __launch_bounds__(256) void k_transpose_all(
    const float* __restrict__ qw, const float* __restrict__ pw,
    const float* __restrict__ f1, const float* __restrict__ f2,
    __bf16* __restrict__ wq, __bf16* __restrict__ wp,
    __bf16* __restrict__ w1, __bf16* __restrict__ w2){
  int id = blockIdx.x;
  size_t l = blockIdx.y;
  const float* W; __bf16* Wt; int K, N, nx, ny;
  if (id < 1728){ W=qw+l*768*2304; Wt=wq+l*768*2304; K=768;  N=2304; nx=id%72; ny=id/72; }
  else if (id < 2304){ id-=1728; W=pw+l*768*768;  Wt=wp+l*768*768;  K=768;  N=768;  nx=id%24; ny=id/24; }
  else if (id < 4608){ id-=2304; W=f1+l*768*3072; Wt=w1+l*768*3072; K=768;  N=3072; nx=id%96; ny=id/96; }
  else {               id-=4608; W=f2+l*3072*768; Wt=w2+l*3072*768; K=3072; N=768;  nx=id%24; ny=id/24; }
  __shared__ float t[32][33];
  int n0 = nx*32, k0 = ny*32;
  int tx = threadIdx.x & 31, ty = threadIdx.x >> 5;
  #pragma unroll
  for (int i = 0; i < 32; i += 8) t[ty+i][tx] = W[(size_t)(k0+ty+i)*N + n0+tx];
  __syncthreads();
  #pragma unroll
  for (int i = 0; i < 32; i += 8) Wt[(size_t)(n0+ty+i)*K + k0+tx] = (__bf16)t[tx][ty+i];
}

// ---------------- bf16 MFMA GEMM, BK=64, XOR-swizzled LDS ----------------
// C[M][N] = A[M][K] @ Bt[N][K]^T ; act: 0 none, 1 relu, 2 gelu(exact)
// BK=64 halves barrier count vs BK=32. LDS [128][64] row stride = 128B would be
// a full bank alias, so the 16B slot index is XOR-swizzled by (row&7): the
// global SOURCE address is pre-swizzled (LDS dest must stay lane-linear for
// global_load_lds) and the ds_read applies the same XOR.

__global__ __launch_bounds__(256) void k_gemm(const __bf16* __restrict__ A, const __bf16* __restrict__ Bt,
    const float* __restrict__ bias, const float* __restrict__ res,
    float* __restrict__ outF, __bf16* __restrict__ outB,
    int M, int N, int K, int act, int splitK){
  __shared__ alignas(16) __bf16 As[128*64];
  __shared__ alignas(16) __bf16 Bs[128*64];
  int tid  = threadIdx.x;
  int m0 = blockIdx.y*128, n0 = blockIdx.x*128;
  int z = blockIdx.z;
  int kLen = K / splitK, k0 = z*kLen;
  int wave = tid >> 6, lane = tid & 63;
  int wm = (wave >> 1)*64, wn = (wave & 1)*64;
  int r16 = lane & 15, q = lane >> 4;
  int srow = tid >> 3;           // staging row 0..31 (base)
  int sslot = tid & 7;           // staging 16B slot within 64-elem row
  int slotX[2];
  #pragma unroll
  for (int kk = 0; kk < 2; kk++) slotX[kk] = ((kk*4 + q) ^ (r16 & 7)) * 8;
  f4 acc[4][4];
  #pragma unroll
  for (int i = 0; i < 4; i++)
    #pragma unroll
    for (int j = 0; j < 4; j++) acc[i][j] = (f4){0.f,0.f,0.f,0.f};

  for (int kt = k0; kt < k0 + kLen; kt += 64){
    #pragma unroll
    for (int rr = 0; rr < 4; rr++){
      int row = rr*32 + srow;
      int scol = kt + ((sslot ^ (row & 7)) * 8);
      int gm = m0 + row; if (gm >= M) gm = M - 1;
      gload16(A  + (size_t)gm*K + scol, (char*)As + rr*4096 + tid*16);
      int gn = n0 + row;
      gload16(Bt + (size_t)gn*K + scol, (char*)Bs + rr*4096 + tid*16);
    }
    __syncthreads();
    #pragma unroll
    for (int kk = 0; kk < 2; kk++){
      bf8 af[4], bq[4];
      #pragma unroll
      for (int i = 0; i < 4; i++) af[i] = *reinterpret_cast<const bf8*>(&As[(wm + i*16 + r16)*64 + slotX[kk]]);
      #pragma unroll
      for (int j = 0; j < 4; j++) bq[j] = *reinterpret_cast<const bf8*>(&Bs[(wn + j*16 + r16)*64 + slotX[kk]]);
      #pragma unroll
      for (int i = 0; i < 4; i++)
        #pragma unroll
        for (int j = 0; j < 4; j++)
          acc[i][j] = __builtin_amdgcn_mfma_f32_16x16x32_bf16(af[i], bq[j], acc[i][j], 0, 0, 0);
    }
    __syncthreads();
  }

  #pragma unroll
  for (int i = 0; i < 4; i++){
    #pragma unroll
    for (int j = 0; j < 4; j++){
      int nn = n0 + wn + j*16 + r16;
      float bv = (bias && z == 0) ? bias[nn] : 0.f;
      #pragma unroll
      for (int r = 0; r < 4; r++){
        int m = m0 + wm + i*16 + q*4 + r;
        if (m >= M) continue;
        float v = acc[i][j][r] + bv;
        if (splitK > 1){
          atomicAdd(&outF[(size_t)m*N + nn], v);
        } else {
          if (act == 1) v = fmaxf(v, 0.f);
          else if (act == 2) v = 0.5f*v*(1.f + erff(v*0.70710678118654752f));
          if (outB){
            outB[(size_t)m*N + nn] = (__bf16)v;
          } else {
            float rv = res ? res[(size_t)m*N + nn] : 0.f;
            outF[(size_t)m*N + nn] = rv + v;
          }
        }
      }
    }
  }
}

// ---------------- layernorm (row = 768) ----------------

__global__ __launch_bounds__(256) void k_ln(const float* __restrict__ in, const float* __restrict__ g,
    const float* __restrict__ bta, __bf16* __restrict__ outB, float* __restrict__ outF, int rowMul){
  int orow = blockIdx.x;
  const float* xr = in + (size_t)orow*rowMul*768;
  int tid = threadIdx.x;
  float v0 = xr[tid], v1 = xr[tid+256], v2 = xr[tid+512];
  float s = v0+v1+v2, s2 = v0*v0 + v1*v1 + v2*v2;
  #pragma unroll
  for (int off = 32; off > 0; off >>= 1){ s += __shfl_xor(s, off); s2 += __shfl_xor(s2, off); }
  __shared__ float rs[4], rq[4];
  int w = tid >> 6;
  if ((tid & 63) == 0){ rs[w] = s; rq[w] = s2; }
  __syncthreads();
  s = rs[0]+rs[1]+rs[2]+rs[3]; s2 = rq[0]+rq[1]+rq[2]+rq[3];
  float mean = s*(1.f/768.f);
  float var  = s2*(1.f/768.f) - mean*mean;
  float rstd = rsqrtf(var + 1e-5f);
  size_t ob = (size_t)orow*768;
  float y0 = (v0-mean)*rstd*g[tid]     + bta[tid];
  float y1 = (v1-mean)*rstd*g[tid+256] + bta[tid+256];
  float y2 = (v2-mean)*rstd*g[tid+512] + bta[tid+512];
  if (outB){ outB[ob+tid]=(__bf16)y0; outB[ob+tid+256]=(__bf16)y1; outB[ob+tid+512]=(__bf16)y2; }
  else     { outF[ob+tid]=y0;         outF[ob+tid+256]=y1;         outF[ob+tid+512]=y2; }
}

// ---------------- MFMA attention: one block per (b,h,half), 64 q-rows/block ----------------
// 768 blocks at 3 blocks/CU (pinned) = one balanced resident round.
// Q,K fragments direct global->register; V transposed in LDS; P in LDS.

#define PSS 136   // Ps row stride (elements): 272B = 17*16B (odd multiple -> spread banks)
#define VTS 136   // Vt row stride (elements)

__global__ __launch_bounds__(256, 3) void k_attn(const __bf16* __restrict__ qkvB, __bf16* __restrict__ o){
  __shared__ alignas(16) __bf16 smem[64*VTS + 64*PSS];
  __bf16* Vt = smem;             // [64][VTS] : Vt[d][t]
  __bf16* Ps = smem + 64*VTS;    // [64][PSS] : local q-rows
  int bh = blockIdx.x >> 1, half = blockIdx.x & 1;
  int b = bh / 12, h = bh % 12;
  int tid = threadIdx.x;
  const __bf16* basep = qkvB + (size_t)(b*101)*2304 + h*64;

  // stage V transposed: 16B coalesced global loads, bank-staggered scalar LDS writes
  #pragma unroll
  for (int it = 0; it < 4; it++){
    int c = tid + it*256;          // [0,1024): 128 t-rows x 8 d-chunks
    int t = c >> 3, d0 = c & 7;
    bf8 v;
    if (t < 101){
      v = *reinterpret_cast<const bf8*>(&basep[(size_t)t*2304 + 1536 + d0*8]);
    } else {
      #pragma unroll
      for (int j = 0; j < 8; j++) v[j] = (__bf16)0.f;
    }
    #pragma unroll
    for (int j = 0; j < 8; j++){
      int jj = (j + d0) & 7;
      Vt[(d0*8 + jj)*VTS + t] = v[jj];
    }
  }

  int wave = tid >> 6, lane = tid & 63;
  int r16 = lane & 15, q = lane >> 4;
  int m0 = half*64 + wave*16;      // global q-row tile base

  // QK^T: direct global fragment loads, no LDS, no barrier
  f4 sacc[7];
  #pragma unroll
  for (int j = 0; j < 7; j++) sacc[j] = (f4){0.f,0.f,0.f,0.f};
  #pragma unroll
  for (int kt = 0; kt < 64; kt += 32){
    int row = m0 + r16; if (row > 100) row = 100;
    bf8 aq = *reinterpret_cast<const bf8*>(&basep[(size_t)row*2304 + kt + q*8]);
    #pragma unroll
    for (int j = 0; j < 7; j++){
      int krow = j*16 + r16; if (krow > 100) krow = 100;
      bf8 kf = *reinterpret_cast<const bf8*>(&basep[(size_t)krow*2304 + 768 + kt + q*8]);
      sacc[j] = __builtin_amdgcn_mfma_f32_16x16x32_bf16(aq, kf, sacc[j], 0, 0, 0);
    }
  }

  // softmax (per row over 7 j-regs x 16 lanes) + write P to LDS (local rows)
  #pragma unroll
  for (int r = 0; r < 4; r++){
    float s[7];
    #pragma unroll
    for (int j = 0; j < 7; j++){
      s[j] = sacc[j][r] * 0.125f;
      if (j == 6 && r16 >= 5) s[j] = -1e30f;
    }
    float mx = s[0];
    #pragma unroll
    for (int j = 1; j < 7; j++) mx = fmaxf(mx, s[j]);
    #pragma unroll
    for (int off2 = 1; off2 < 16; off2 <<= 1) mx = fmaxf(mx, __shfl_xor(mx, off2));
    float p[7], sum = 0.f;
    #pragma unroll
    for (int j = 0; j < 7; j++){ p[j] = __expf(s[j] - mx); sum += p[j]; }
    #pragma unroll
    for (int off2 = 1; off2 < 16; off2 <<= 1) sum += __shfl_xor(sum, off2);
    float inv = 1.f / sum;
    int lr = wave*16 + q*4 + r;
    #pragma unroll
    for (int j = 0; j < 7; j++) Ps[lr*PSS + j*16 + r16] = (__bf16)(p[j]*inv);
    Ps[lr*PSS + 112 + r16] = (__bf16)0.f;
  }
  __syncthreads();

  // PV: A from Ps, B from Vt — single ds_read_b128 per fragment
  f4 oacc[4];
  #pragma unroll
  for (int n = 0; n < 4; n++) oacc[n] = (f4){0.f,0.f,0.f,0.f};
  #pragma unroll
  for (int kt = 0; kt < 128; kt += 32){
    bf8 af = *reinterpret_cast<const bf8*>(&Ps[(wave*16 + r16)*PSS + kt + q*8]);
    #pragma unroll
    for (int n = 0; n < 4; n++){
      bf8 bq = *reinterpret_cast<const bf8*>(&Vt[(n*16 + r16)*VTS + kt + q*8]);
      oacc[n] = __builtin_amdgcn_mfma_f32_16x16x32_bf16(af, bq, oacc[n], 0, 0, 0);
    }
  }

  #pragma unroll
  for (int n = 0; n < 4; n++){
    #pragma unroll
    for (int r = 0; r < 4; r++){
      int t = m0 + q*4 + r;
      if (t < 101)
        o[((size_t)(b*101 + t))*768 + h*64 + n*16 + r16] = (__bf16)oacc[n][r];
    }
  }
}

__global__ void k_head(const float* __restrict__ cls, const float* __restrict__ hw,
                       const float* __restrict__ hb, float* __restrict__ out){
  int b = blockIdx.x, c = threadIdx.x;
  if (c < 40){
    float s = hb[c];
    for (int k = 0; k < 768; k++) s += cls[b*768 + k]*hw[k*40 + c];
    out[b*40 + c] = s;
  }
}

// ---------------- launch ----------------

extern "C" void kernel_launch(void* const* d_in, const int* in_sizes, int n_in,
                              void* d_out, int out_size, void* d_ws, size_t ws_size,
                              hipStream_t stream){
  const float* x       = (const float*)d_in[0];
  const float* W1      = (const float*)d_in[1];
  const float* W2      = (const float*)d_in[2];
  const float* W3      = (const float*)d_in[3];
  const float* Wa      = (const float*)d_in[4];
  const float* bn_g    = (const float*)d_in[5];
  const float* bn_b    = (const float*)d_in[6];
  const float* bn_mean = (const float*)d_in[7];
  const float* bn_var  = (const float*)d_in[8];
  const float* cls_t   = (const float*)d_in[9];
  const float* pos     = (const float*)d_in[10];
  const float* ln1_g   = (const float*)d_in[11];
  const float* ln1_b   = (const float*)d_in[12];
  const float* qkv_w   = (const float*)d_in[13];
  const float* proj_w  = (const float*)d_in[14];
  const float* proj_b  = (const float*)d_in[15];
  const float* ln2_g   = (const float*)d_in[16];
  const float* ln2_b   = (const float*)d_in[17];
  const float* fc1_w   = (const float*)d_in[18];
  const float* fc1_b   = (const float*)d_in[19];
  const float* fc2_w   = (const float*)d_in[20];
  const float* fc2_b   = (const float*)d_in[21];
  const float* norm_g  = (const float*)d_in[22];
  const float* norm_b  = (const float*)d_in[23];
  const float* head_w  = (const float*)d_in[24];
  const float* head_b  = (const float*)d_in[25];

  char* ws = (char*)d_ws;
  size_t off = 0;
  auto alloc = [&](size_t bytes)->void*{ void* p = ws + off; off += (bytes + 255) & ~(size_t)255; return p; };
  // --- persistent region ---
  float* cnt     = (float*)alloc(3200*4);
  float* cent    = (float*)alloc(3200*3*4);
  float* pillar  = (float*)alloc((size_t)3200*768*4);
  size_t zbytes  = (size_t)((char*)pillar - (char*)cnt) + (size_t)3200*768*4;
  int*   base    = (int*)  alloc(3200*4);
  int*   wptr    = (int*)  alloc(3200*4);
  int*   order   = (int*)  alloc((size_t)65536*4);
  int*   cellSlot= (int*)  alloc((size_t)65536*4);
  int*   cellArr = (int*)  alloc((size_t)65536*4);
  float* pooled  = (float*)alloc((size_t)3200*128*4);
  float* tokens  = (float*)alloc((size_t)3232*768*4);
  float* cls     = (float*)alloc((size_t)32*768*4);
  __bf16* wWa    = (__bf16*)alloc((size_t)768*256*2);
  // all-layer transposed weights (persistent through the transformer loop)
  __bf16* wq12   = (__bf16*)alloc((size_t)12*768*2304*2);
  __bf16* wp12   = (__bf16*)alloc((size_t)12*768*768*2);
  __bf16* w112   = (__bf16*)alloc((size_t)12*768*3072*2);
  __bf16* w212   = (__bf16*)alloc((size_t)12*3072*768*2);
  // --- overlaid region R ---
  size_t offR = off;
  __bf16* A2  = (__bf16*)alloc((size_t)65536*256*2);
  __bf16* h2c = (__bf16*)alloc((size_t)16384*768*2);
  size_t endPillarPhase = off;
  off = offR;
  __bf16* y    = (__bf16*)alloc((size_t)3232*768*2);
  __bf16* qkvB = (__bf16*)alloc((size_t)3232*2304*2);
  __bf16* o    = (__bf16*)alloc((size_t)3232*768*2);
  __bf16* mlp  = (__bf16*)alloc((size_t)3232*3072*2);
  if (off < endPillarPhase) off = endPillarPhase;
  (void)ws_size; (void)in_sizes; (void)n_in; (void)out_size;

  hipMemsetAsync(cnt, 0, zbytes, stream);

  // all weight transposes upfront (one dispatch for 12 layers)
  k_transpose_all<<<dim3(6912,12),256,0,stream>>>(qkv_w, proj_w, fc1_w, fc2_w, wq12, wp12, w112, w212);
  k_transpose<<<dim3(24,8),256,0,stream>>>(Wa, wWa, 256, 768);

  // pillar feature stage
  k_cell<<<256,256,0,stream>>>(x, cellArr, cnt, cent);
  k_scan<<<1,256,0,stream>>>(cnt, base, wptr);
  k_scatter<<<256,256,0,stream>>>(cellArr, wptr, order);
  k_pointmlp<<<256,256,0,stream>>>(x, W1, W2, W3, cent, cnt, cellArr, order, cellSlot, A2);
  k_poolh<<<3200,128,0,stream>>>(A2, base, cnt, pooled);
  k_fill<<<4096,256,0,stream>>>(pooled, cellSlot, A2);
  for (int c = 0; c < 4; c++){
    k_gemm<<<dim3(6,128),256,0,stream>>>(A2 + (size_t)c*16384*256, wWa, nullptr, nullptr,
                                         nullptr, h2c, 16384, 768, 256, 1, 1);
    k_pillarpool<<<3200,256,0,stream>>>(h2c, base, cnt, pillar, c*16384);
  }
  k_assemble<<<9696,256,0,stream>>>(pillar, bn_g, bn_b, bn_mean, bn_var, cls_t, pos, tokens);

  // transformer
  for (int l = 0; l < 12; l++){
    __bf16* wq = wq12 + (size_t)l*768*2304;
    __bf16* wp = wp12 + (size_t)l*768*768;
    __bf16* w1 = w112 + (size_t)l*768*3072;
    __bf16* w2 = w212 + (size_t)l*3072*768;
    k_ln<<<3232,256,0,stream>>>(tokens, ln1_g + l*768, ln1_b + l*768, y, nullptr, 1);
    k_gemm<<<dim3(18,26),256,0,stream>>>(y, wq, nullptr, nullptr, nullptr, qkvB, 3232, 2304, 768, 0, 1);
    k_attn<<<768,256,0,stream>>>(qkvB, o);
    // proj: split-K=4, atomic += into tokens (tokens already holds residual h)
    k_gemm<<<dim3(6,26,4),256,0,stream>>>(o, wp, proj_b + l*768, nullptr, tokens, nullptr,
                                          3232, 768, 768, 0, 4);
    k_ln<<<3232,256,0,stream>>>(tokens, ln2_g + l*768, ln2_b + l*768, y, nullptr, 1);
    k_gemm<<<dim3(24,26),256,0,stream>>>(y, w1, fc1_b + l*3072, nullptr, nullptr, mlp, 3232, 3072, 768, 2, 1);
    // fc2: split-K=4, atomic += into tokens
    k_gemm<<<dim3(6,26,4),256,0,stream>>>(mlp, w2, fc2_b + l*768, nullptr, tokens, nullptr,
                                          3232, 768, 3072, 0, 4);
  }

  k_ln<<<32,256,0,stream>>>(tokens, norm_g, norm_b, nullptr, cls, 101);
  k_head<<<32,64,0,stream>>>(cls, head_w, head_b, (float*)d_out);
}

// Round 4
// 2832.373 us; speedup vs baseline: 1.3641x; 1.0261x over previous
//
#include <hip/hip_runtime.h>

typedef __bf16 bf8 __attribute__((ext_vector_type(8)));
typedef float  f4  __attribute__((ext_vector_type(4)));
typedef unsigned long long uptr;

__device__ __forceinline__ void gload16(const void* g, void* l){
  __builtin_amdgcn_global_load_lds(
      (const __attribute__((address_space(1))) unsigned int*)(uptr)g,
      (__attribute__((address_space(3))) unsigned int*)(uptr)l,
      16, 0, 0);
}

// ---------------- pillar stage ----------------

__global__ __launch_bounds__(256) void k_cell(const float* __restrict__ x, int* __restrict__ cellArr,
                                              float* __restrict__ cnt, float* __restrict__ cent){
  int p = blockIdx.x*256 + threadIdx.x;            // 65536 points
  float x0 = x[p*3+0], x1 = x[p*3+1], x2 = x[p*3+2];
  float y0 = fminf(fmaxf(x0 + 1.0f, 0.0f), 1.99f);
  float y1 = fminf(fmaxf(x2 + 1.0f, 0.0f), 1.99f);
  int i0 = (int)floorf(y0 / 0.2f);
  int i1 = (int)floorf(y1 / 0.2f);
  int b = p >> 11;
  int cell = b*100 + i0*10 + i1;
  cellArr[p] = cell;
  atomicAdd(&cnt[cell], 1.0f);
  atomicAdd(&cent[cell*3+0], x1);
  atomicAdd(&cent[cell*3+1], x0);
  atomicAdd(&cent[cell*3+2], x2);
}

// counting-sort scan: base = exclusive prefix of cnt; wptr = copy of base
__global__ __launch_bounds__(256) void k_scan(const float* __restrict__ cnt,
                                              int* __restrict__ base, int* __restrict__ wptr){
  __shared__ int a[256];
  int tid = threadIdx.x;
  int start = tid*13, end = start+13; if (end > 3200) end = 3200;
  int local = 0;
  for (int i = start; i < end; i++) local += (int)cnt[i];
  a[tid] = local;
  __syncthreads();
  for (int off = 1; off < 256; off <<= 1){
    int t = (tid >= off) ? a[tid - off] : 0;
    __syncthreads();
    a[tid] += t;
    __syncthreads();
  }
  int run = a[tid] - local;
  for (int i = start; i < end; i++){
    base[i] = run; wptr[i] = run;
    run += (int)cnt[i];
  }
}

__global__ __launch_bounds__(256) void k_scatter(const int* __restrict__ cellArr,
                                                 int* __restrict__ wptr, int* __restrict__ order){
  int p = blockIdx.x*256 + threadIdx.x;
  int c = cellArr[p];
  int pos = atomicAdd(&wptr[c], 1);
  order[pos] = p;
}

__global__ __launch_bounds__(256) void k_pointmlp(const float* __restrict__ x,
    const float* __restrict__ W1, const float* __restrict__ W2, const float* __restrict__ W3,
    const float* __restrict__ cent, const float* __restrict__ cnt, const int* __restrict__ cellArr,
    const int* __restrict__ order, int* __restrict__ cellSlot, __bf16* __restrict__ A2){
  __shared__ float w1s[6*32];
  __shared__ float w2s[32*64];
  __shared__ float w3s[64*128];
  int tid = threadIdx.x;
  for (int i = tid; i < 192;  i += 256) w1s[i] = W1[i];
  for (int i = tid; i < 2048; i += 256) w2s[i] = W2[i];
  for (int i = tid; i < 8192; i += 256) w3s[i] = W3[i];
  __syncthreads();
  int s = blockIdx.x*256 + tid;                 // sorted slot
  int p = order[s];
  int cell = cellArr[p];
  cellSlot[s] = cell;
  float pf0 = x[p*3+1], pf1 = x[p*3+0], pf2 = x[p*3+2];
  float cc = fmaxf(cnt[cell], 1.0f);
  float a[6] = {pf0, pf1, pf2,
                pf0 - cent[cell*3+0]/cc, pf1 - cent[cell*3+1]/cc, pf2 - cent[cell*3+2]/cc};
  float h1[32];
  #pragma unroll
  for (int f = 0; f < 32; f++){
    float t = 0.f;
    #pragma unroll
    for (int i = 0; i < 6; i++) t += a[i]*w1s[i*32+f];
    h1[f] = fmaxf(t, 0.f);
  }
  float h2[64];
  #pragma unroll
  for (int f = 0; f < 64; f++){
    float t = 0.f;
    #pragma unroll
    for (int i = 0; i < 32; i++) t += h1[i]*w2s[i*64+f];
    h2[f] = fmaxf(t, 0.f);
  }
  for (int f0 = 0; f0 < 128; f0 += 8){
    __bf16 tmp[8];
    #pragma unroll
    for (int j = 0; j < 8; j++){
      float t = 0.f;
      #pragma unroll
      for (int i = 0; i < 64; i++) t += h2[i]*w3s[i*128+f0+j];
      tmp[j] = (__bf16)fmaxf(t, 0.f);
    }
    *reinterpret_cast<uint4*>(&A2[(size_t)s*256 + f0]) = *reinterpret_cast<uint4*>(tmp);
  }
}

__global__ __launch_bounds__(128) void k_poolh(const __bf16* __restrict__ A2,
    const int* __restrict__ base, const float* __restrict__ cnt, float* __restrict__ pooled){
  int c = blockIdx.x, f = threadIdx.x;
  int b0 = base[c], n = (int)cnt[c];
  float v = 0.f;
  for (int k = 0; k < n; k++) v = fmaxf(v, (float)A2[(size_t)(b0+k)*256 + f]);
  pooled[c*128 + f] = v;
}

__global__ __launch_bounds__(256) void k_fill(const float* __restrict__ pooled,
    const int* __restrict__ cellSlot, __bf16* __restrict__ A2){
  int idx = blockIdx.x*256 + threadIdx.x;       // 65536*16
  int s = idx >> 4, f0 = (idx & 15) << 3;
  int cell = cellSlot[s];
  const float* pp = &pooled[cell*128 + f0];
  __bf16 tmp[8];
  #pragma unroll
  for (int j = 0; j < 8; j++) tmp[j] = (__bf16)pp[j];
  *reinterpret_cast<uint4*>(&A2[(size_t)s*256 + 128 + f0]) = *reinterpret_cast<uint4*>(tmp);
}

// one block per cell, plain store (single dispatch covers full slot range)
__global__ __launch_bounds__(256) void k_pillarpool(const __bf16* __restrict__ h2c,
    const int* __restrict__ base, const float* __restrict__ cnt, float* __restrict__ pillar){
  int c = blockIdx.x, tid = threadIdx.x;
  int b0 = base[c], n = (int)cnt[c];
  if (n == 0) return;                    // pillar stays 0 from memset
  for (int f = tid; f < 768; f += 256){
    float v = 0.f;
    for (int s = b0; s < b0 + n; s++) v = fmaxf(v, (float)h2c[(size_t)s*768 + f]);
    pillar[(size_t)c*768 + f] = v;
  }
}

__global__ void k_assemble(const float* __restrict__ pillar,
    const float* __restrict__ bn_g, const float* __restrict__ bn_b,
    const float* __restrict__ bn_mean, const float* __restrict__ bn_var,
    const float* __restrict__ cls_t, const float* __restrict__ pos,
    float* __restrict__ tokens){
  int idx = blockIdx.x*256 + threadIdx.x;          // 3232*768
  int m = idx / 768, d = idx % 768;
  int b = m / 101, t = m % 101;
  float v;
  if (t == 0) v = cls_t[d];
  else {
    int s = t - 1;
    float pv = pillar[((size_t)b*100 + s)*768 + d];
    float inv = bn_g[s]*rsqrtf(bn_var[s] + 1e-5f);
    v = (pv - bn_mean[s])*inv + bn_b[s];
  }
  tokens[idx] = v + pos[t*768 + d];
}

// ---------------- weight transpose-convert ----------------

__global__ __launch_bounds__(256) void k_transpose(const float* __restrict__ W, __bf16* __restrict__ Wt,
                                                   int K, int N){
  __shared__ float t[32][33];
  int n0 = blockIdx.x*32, k0 = blockIdx.y*32;
  int tx = threadIdx.x & 31, ty = threadIdx.x >> 5;
  #pragma unroll
  for (int i = 0; i < 32; i += 8){
    int k = k0 + ty + i, n = n0 + tx;
    t[ty+i][tx] = (k < K && n < N) ? W[(size_t)k*N + n] : 0.f;
  }
  __syncthreads();
  #pragma unroll
  for (int i = 0; i < 32; i += 8){
    int n = n0 + ty + i, k = k0 + tx;
    if (n < N && k < K) Wt[(size_t)n*K + k] = (__bf16)t[tx][ty+i];
  }
}

// all 12 layers in one dispatch: grid (1728, 12).
// [128 k x 32 n] tiles: float4 reads, uint4 writes (256B contiguous per 16 lanes).
__global__ __launch_bounds__(256) void k_transpose_all(
    const float* __restrict__ qw, const float* __restrict__ pw,
    const float* __restrict__ f1, const float* __restrict__ f2,
    __bf16* __restrict__ wq, __bf16* __restrict__ wp,
    __bf16* __restrict__ w1, __bf16* __restrict__ w2){
  int id = blockIdx.x;
  size_t l = blockIdx.y;
  const float* W; __bf16* Wt; int K, N, kx, nx;
  if (id < 432){               W=qw+l*768*2304; Wt=wq+l*768*2304; K=768;  N=2304; kx=id%6;  nx=id/6; }
  else if (id < 576){ id-=432; W=pw+l*768*768;  Wt=wp+l*768*768;  K=768;  N=768;  kx=id%6;  nx=id/6; }
  else if (id < 1152){ id-=576;  W=f1+l*768*3072; Wt=w1+l*768*3072; K=768;  N=3072; kx=id%6;  nx=id/6; }
  else {               id-=1152; W=f2+l*3072*768; Wt=w2+l*3072*768; K=3072; N=768;  kx=id%24; nx=id/24; }
  __shared__ __bf16 t[32][136];
  int k0 = kx*128, n0 = nx*32;
  int tid = threadIdx.x;
  int kr = tid >> 3, nc = (tid & 7)*4;
  #pragma unroll
  for (int i = 0; i < 4; i++){
    int k = kr + i*32;
    float4 v = *reinterpret_cast<const float4*>(&W[(size_t)(k0+k)*N + n0 + nc]);
    t[nc+0][k] = (__bf16)v.x; t[nc+1][k] = (__bf16)v.y;
    t[nc+2][k] = (__bf16)v.z; t[nc+3][k] = (__bf16)v.w;
  }
  __syncthreads();
  int nr = tid >> 4, ks = (tid & 15)*8;
  #pragma unroll
  for (int j = 0; j < 2; j++){
    int n = j*16 + nr;
    *reinterpret_cast<uint4*>(&Wt[(size_t)(n0+n)*K + k0 + ks]) = *reinterpret_cast<uint4*>(&t[n][ks]);
  }
}

// ---------------- bf16 MFMA GEMM, BK=64, XOR-swizzled LDS ----------------
// C[M][N] = A[M][K] @ Bt[N][K]^T ; act: 0 none, 1 relu, 2 gelu(exact)

__global__ __launch_bounds__(256) void k_gemm(const __bf16* __restrict__ A, const __bf16* __restrict__ Bt,
    const float* __restrict__ bias, const float* __restrict__ res,
    float* __restrict__ outF, __bf16* __restrict__ outB,
    int M, int N, int K, int act, int splitK){
  __shared__ alignas(16) __bf16 As[128*64];
  __shared__ alignas(16) __bf16 Bs[128*64];
  int tid  = threadIdx.x;
  int m0 = blockIdx.y*128, n0 = blockIdx.x*128;
  int z = blockIdx.z;
  int kLen = K / splitK, k0 = z*kLen;
  int wave = tid >> 6, lane = tid & 63;
  int wm = (wave >> 1)*64, wn = (wave & 1)*64;
  int r16 = lane & 15, q = lane >> 4;
  int srow = tid >> 3;           // staging row 0..31 (base)
  int sslot = tid & 7;           // staging 16B slot within 64-elem row
  int slotX[2];
  #pragma unroll
  for (int kk = 0; kk < 2; kk++) slotX[kk] = ((kk*4 + q) ^ (r16 & 7)) * 8;
  f4 acc[4][4];
  #pragma unroll
  for (int i = 0; i < 4; i++)
    #pragma unroll
    for (int j = 0; j < 4; j++) acc[i][j] = (f4){0.f,0.f,0.f,0.f};

  for (int kt = k0; kt < k0 + kLen; kt += 64){
    #pragma unroll
    for (int rr = 0; rr < 4; rr++){
      int row = rr*32 + srow;
      int scol = kt + ((sslot ^ (row & 7)) * 8);
      int gm = m0 + row; if (gm >= M) gm = M - 1;
      gload16(A  + (size_t)gm*K + scol, (char*)As + rr*4096 + tid*16);
      int gn = n0 + row;
      gload16(Bt + (size_t)gn*K + scol, (char*)Bs + rr*4096 + tid*16);
    }
    __syncthreads();
    #pragma unroll
    for (int kk = 0; kk < 2; kk++){
      bf8 af[4], bq[4];
      #pragma unroll
      for (int i = 0; i < 4; i++) af[i] = *reinterpret_cast<const bf8*>(&As[(wm + i*16 + r16)*64 + slotX[kk]]);
      #pragma unroll
      for (int j = 0; j < 4; j++) bq[j] = *reinterpret_cast<const bf8*>(&Bs[(wn + j*16 + r16)*64 + slotX[kk]]);
      #pragma unroll
      for (int i = 0; i < 4; i++)
        #pragma unroll
        for (int j = 0; j < 4; j++)
          acc[i][j] = __builtin_amdgcn_mfma_f32_16x16x32_bf16(af[i], bq[j], acc[i][j], 0, 0, 0);
    }
    __syncthreads();
  }

  #pragma unroll
  for (int i = 0; i < 4; i++){
    #pragma unroll
    for (int j = 0; j < 4; j++){
      int nn = n0 + wn + j*16 + r16;
      float bv = (bias && z == 0) ? bias[nn] : 0.f;
      #pragma unroll
      for (int r = 0; r < 4; r++){
        int m = m0 + wm + i*16 + q*4 + r;
        if (m >= M) continue;
        float v = acc[i][j][r] + bv;
        if (splitK > 1){
          atomicAdd(&outF[(size_t)m*N + nn], v);
        } else {
          if (act == 1) v = fmaxf(v, 0.f);
          else if (act == 2) v = 0.5f*v*(1.f + erff(v*0.70710678118654752f));
          if (outB){
            outB[(size_t)m*N + nn] = (__bf16)v;
          } else {
            float rv = res ? res[(size_t)m*N + nn] : 0.f;
            outF[(size_t)m*N + nn] = rv + v;
          }
        }
      }
    }
  }
}

// ---------------- layernorm (row = 768) ----------------

__global__ __launch_bounds__(256) void k_ln(const float* __restrict__ in, const float* __restrict__ g,
    const float* __restrict__ bta, __bf16* __restrict__ outB, float* __restrict__ outF, int rowMul){
  int orow = blockIdx.x;
  const float* xr = in + (size_t)orow*rowMul*768;
  int tid = threadIdx.x;
  float v0 = xr[tid], v1 = xr[tid+256], v2 = xr[tid+512];
  float s = v0+v1+v2, s2 = v0*v0 + v1*v1 + v2*v2;
  #pragma unroll
  for (int off = 32; off > 0; off >>= 1){ s += __shfl_xor(s, off); s2 += __shfl_xor(s2, off); }
  __shared__ float rs[4], rq[4];
  int w = tid >> 6;
  if ((tid & 63) == 0){ rs[w] = s; rq[w] = s2; }
  __syncthreads();
  s = rs[0]+rs[1]+rs[2]+rs[3]; s2 = rq[0]+rq[1]+rq[2]+rq[3];
  float mean = s*(1.f/768.f);
  float var  = s2*(1.f/768.f) - mean*mean;
  float rstd = rsqrtf(var + 1e-5f);
  size_t ob = (size_t)orow*768;
  float y0 = (v0-mean)*rstd*g[tid]     + bta[tid];
  float y1 = (v1-mean)*rstd*g[tid+256] + bta[tid+256];
  float y2 = (v2-mean)*rstd*g[tid+512] + bta[tid+512];
  if (outB){ outB[ob+tid]=(__bf16)y0; outB[ob+tid+256]=(__bf16)y1; outB[ob+tid+512]=(__bf16)y2; }
  else     { outF[ob+tid]=y0;         outF[ob+tid+256]=y1;         outF[ob+tid+512]=y2; }
}

// ---------------- MFMA attention: one block per (b,h,half), 64 q-rows/block ----------------

#define PSS 136   // Ps row stride (elements)
#define VTS 136   // Vt row stride (elements)

__global__ __launch_bounds__(256, 3) void k_attn(const __bf16* __restrict__ qkvB, __bf16* __restrict__ o){
  __shared__ alignas(16) __bf16 smem[64*VTS + 64*PSS];
  __bf16* Vt = smem;             // [64][VTS] : Vt[d][t]
  __bf16* Ps = smem + 64*VTS;    // [64][PSS] : local q-rows
  int bh = blockIdx.x >> 1, half = blockIdx.x & 1;
  int b = bh / 12, h = bh % 12;
  int tid = threadIdx.x;
  const __bf16* basep = qkvB + (size_t)(b*101)*2304 + h*64;

  // stage V transposed: 16B coalesced global loads, bank-staggered scalar LDS writes
  #pragma unroll
  for (int it = 0; it < 4; it++){
    int c = tid + it*256;          // [0,1024): 128 t-rows x 8 d-chunks
    int t = c >> 3, d0 = c & 7;
    bf8 v;
    if (t < 101){
      v = *reinterpret_cast<const bf8*>(&basep[(size_t)t*2304 + 1536 + d0*8]);
    } else {
      #pragma unroll
      for (int j = 0; j < 8; j++) v[j] = (__bf16)0.f;
    }
    #pragma unroll
    for (int j = 0; j < 8; j++){
      int jj = (j + d0) & 7;
      Vt[(d0*8 + jj)*VTS + t] = v[jj];
    }
  }

  int wave = tid >> 6, lane = tid & 63;
  int r16 = lane & 15, q = lane >> 4;
  int m0 = half*64 + wave*16;      // global q-row tile base

  // QK^T: direct global fragment loads, no LDS, no barrier
  f4 sacc[7];
  #pragma unroll
  for (int j = 0; j < 7; j++) sacc[j] = (f4){0.f,0.f,0.f,0.f};
  #pragma unroll
  for (int kt = 0; kt < 64; kt += 32){
    int row = m0 + r16; if (row > 100) row = 100;
    bf8 aq = *reinterpret_cast<const bf8*>(&basep[(size_t)row*2304 + kt + q*8]);
    #pragma unroll
    for (int j = 0; j < 7; j++){
      int krow = j*16 + r16; if (krow > 100) krow = 100;
      bf8 kf = *reinterpret_cast<const bf8*>(&basep[(size_t)krow*2304 + 768 + kt + q*8]);
      sacc[j] = __builtin_amdgcn_mfma_f32_16x16x32_bf16(aq, kf, sacc[j], 0, 0, 0);
    }
  }

  // softmax + write P to LDS (local rows)
  #pragma unroll
  for (int r = 0; r < 4; r++){
    float s[7];
    #pragma unroll
    for (int j = 0; j < 7; j++){
      s[j] = sacc[j][r] * 0.125f;
      if (j == 6 && r16 >= 5) s[j] = -1e30f;
    }
    float mx = s[0];
    #pragma unroll
    for (int j = 1; j < 7; j++) mx = fmaxf(mx, s[j]);
    #pragma unroll
    for (int off2 = 1; off2 < 16; off2 <<= 1) mx = fmaxf(mx, __shfl_xor(mx, off2));
    float p[7], sum = 0.f;
    #pragma unroll
    for (int j = 0; j < 7; j++){ p[j] = __expf(s[j] - mx); sum += p[j]; }
    #pragma unroll
    for (int off2 = 1; off2 < 16; off2 <<= 1) sum += __shfl_xor(sum, off2);
    float inv = 1.f / sum;
    int lr = wave*16 + q*4 + r;
    #pragma unroll
    for (int j = 0; j < 7; j++) Ps[lr*PSS + j*16 + r16] = (__bf16)(p[j]*inv);
    Ps[lr*PSS + 112 + r16] = (__bf16)0.f;
  }
  __syncthreads();

  // PV: A from Ps, B from Vt — single ds_read_b128 per fragment
  f4 oacc[4];
  #pragma unroll
  for (int n = 0; n < 4; n++) oacc[n] = (f4){0.f,0.f,0.f,0.f};
  #pragma unroll
  for (int kt = 0; kt < 128; kt += 32){
    bf8 af = *reinterpret_cast<const bf8*>(&Ps[(wave*16 + r16)*PSS + kt + q*8]);
    #pragma unroll
    for (int n = 0; n < 4; n++){
      bf8 bq = *reinterpret_cast<const bf8*>(&Vt[(n*16 + r16)*VTS + kt + q*8]);
      oacc[n] = __builtin_amdgcn_mfma_f32_16x16x32_bf16(af, bq, oacc[n], 0, 0, 0);
    }
  }

  #pragma unroll
  for (int n = 0; n < 4; n++){
    #pragma unroll
    for (int r = 0; r < 4; r++){
      int t = m0 + q*4 + r;
      if (t < 101)
        o[((size_t)(b*101 + t))*768 + h*64 + n*16 + r16] = (__bf16)oacc[n][r];
    }
  }
}

__global__ __launch_bounds__(256) void k_head(const float* __restrict__ cls, const float* __restrict__ hw,
                       const float* __restrict__ hb, float* __restrict__ out){
  int b = blockIdx.x;
  int tid = threadIdx.x;
  int c = tid % 40, s = tid / 40;   // s in 0..6 (tid>=240 idle)
  __shared__ float part[6][40];
  if (s < 6){
    float acc = 0.f;
    for (int k = s*128; k < s*128 + 128; k++) acc += cls[b*768 + k]*hw[k*40 + c];
    part[s][c] = acc;
  }
  __syncthreads();
  if (tid < 40){
    float v = hb[tid];
    #pragma unroll
    for (int i = 0; i < 6; i++) v += part[i][tid];
    out[b*40 + tid] = v;
  }
}

// ---------------- launch ----------------

extern "C" void kernel_launch(void* const* d_in, const int* in_sizes, int n_in,
                              void* d_out, int out_size, void* d_ws, size_t ws_size,
                              hipStream_t stream){
  const float* x       = (const float*)d_in[0];
  const float* W1      = (const float*)d_in[1];
  const float* W2      = (const float*)d_in[2];
  const float* W3      = (const float*)d_in[3];
  const float* Wa      = (const float*)d_in[4];
  const float* bn_g    = (const float*)d_in[5];
  const float* bn_b    = (const float*)d_in[6];
  const float* bn_mean = (const float*)d_in[7];
  const float* bn_var  = (const float*)d_in[8];
  const float* cls_t   = (const float*)d_in[9];
  const float* pos     = (const float*)d_in[10];
  const float* ln1_g   = (const float*)d_in[11];
  const float* ln1_b   = (const float*)d_in[12];
  const float* qkv_w   = (const float*)d_in[13];
  const float* proj_w  = (const float*)d_in[14];
  const float* proj_b  = (const float*)d_in[15];
  const float* ln2_g   = (const float*)d_in[16];
  const float* ln2_b   = (const float*)d_in[17];
  const float* fc1_w   = (const float*)d_in[18];
  const float* fc1_b   = (const float*)d_in[19];
  const float* fc2_w   = (const float*)d_in[20];
  const float* fc2_b   = (const float*)d_in[21];
  const float* norm_g  = (const float*)d_in[22];
  const float* norm_b  = (const float*)d_in[23];
  const float* head_w  = (const float*)d_in[24];
  const float* head_b  = (const float*)d_in[25];

  char* ws = (char*)d_ws;
  size_t off = 0;
  auto alloc = [&](size_t bytes)->void*{ void* p = ws + off; off += (bytes + 255) & ~(size_t)255; return p; };
  // --- persistent region ---
  float* cnt     = (float*)alloc(3200*4);
  float* cent    = (float*)alloc(3200*3*4);
  float* pillar  = (float*)alloc((size_t)3200*768*4);
  size_t zbytes  = (size_t)((char*)pillar - (char*)cnt) + (size_t)3200*768*4;
  int*   base    = (int*)  alloc(3200*4);
  int*   wptr    = (int*)  alloc(3200*4);
  int*   order   = (int*)  alloc((size_t)65536*4);
  int*   cellSlot= (int*)  alloc((size_t)65536*4);
  int*   cellArr = (int*)  alloc((size_t)65536*4);
  float* pooled  = (float*)alloc((size_t)3200*128*4);
  float* tokens  = (float*)alloc((size_t)3232*768*4);
  float* cls     = (float*)alloc((size_t)32*768*4);
  __bf16* wWa    = (__bf16*)alloc((size_t)768*256*2);
  // all-layer transposed weights (persistent through the transformer loop)
  __bf16* wq12   = (__bf16*)alloc((size_t)12*768*2304*2);
  __bf16* wp12   = (__bf16*)alloc((size_t)12*768*768*2);
  __bf16* w112   = (__bf16*)alloc((size_t)12*768*3072*2);
  __bf16* w212   = (__bf16*)alloc((size_t)12*3072*768*2);
  // --- overlaid region R ---
  size_t offR = off;
  __bf16* A2  = (__bf16*)alloc((size_t)65536*256*2);
  __bf16* h2c = (__bf16*)alloc((size_t)65536*768*2);
  size_t endPillarPhase = off;
  off = offR;
  __bf16* y    = (__bf16*)alloc((size_t)3232*768*2);
  __bf16* qkvB = (__bf16*)alloc((size_t)3232*2304*2);
  __bf16* o    = (__bf16*)alloc((size_t)3232*768*2);
  __bf16* mlp  = (__bf16*)alloc((size_t)3232*3072*2);
  if (off < endPillarPhase) off = endPillarPhase;
  (void)ws_size; (void)in_sizes; (void)n_in; (void)out_size;

  hipMemsetAsync(cnt, 0, zbytes, stream);

  // all weight transposes upfront (one dispatch for 12 layers)
  k_transpose_all<<<dim3(1728,12),256,0,stream>>>(qkv_w, proj_w, fc1_w, fc2_w, wq12, wp12, w112, w212);
  k_transpose<<<dim3(24,8),256,0,stream>>>(Wa, wWa, 256, 768);

  // pillar feature stage
  k_cell<<<256,256,0,stream>>>(x, cellArr, cnt, cent);
  k_scan<<<1,256,0,stream>>>(cnt, base, wptr);
  k_scatter<<<256,256,0,stream>>>(cellArr, wptr, order);
  k_pointmlp<<<256,256,0,stream>>>(x, W1, W2, W3, cent, cnt, cellArr, order, cellSlot, A2);
  k_poolh<<<3200,128,0,stream>>>(A2, base, cnt, pooled);
  k_fill<<<4096,256,0,stream>>>(pooled, cellSlot, A2);
  k_gemm<<<dim3(6,512),256,0,stream>>>(A2, wWa, nullptr, nullptr, nullptr, h2c, 65536, 768, 256, 1, 1);
  k_pillarpool<<<3200,256,0,stream>>>(h2c, base, cnt, pillar);
  k_assemble<<<9696,256,0,stream>>>(pillar, bn_g, bn_b, bn_mean, bn_var, cls_t, pos, tokens);

  // transformer
  for (int l = 0; l < 12; l++){
    __bf16* wq = wq12 + (size_t)l*768*2304;
    __bf16* wp = wp12 + (size_t)l*768*768;
    __bf16* w1 = w112 + (size_t)l*768*3072;
    __bf16* w2 = w212 + (size_t)l*3072*768;
    k_ln<<<3232,256,0,stream>>>(tokens, ln1_g + l*768, ln1_b + l*768, y, nullptr, 1);
    k_gemm<<<dim3(18,26),256,0,stream>>>(y, wq, nullptr, nullptr, nullptr, qkvB, 3232, 2304, 768, 0, 1);
    k_attn<<<768,256,0,stream>>>(qkvB, o);
    // proj: split-K=4, atomic += into tokens (tokens already holds residual h)
    k_gemm<<<dim3(6,26,4),256,0,stream>>>(o, wp, proj_b + l*768, nullptr, tokens, nullptr,
                                          3232, 768, 768, 0, 4);
    k_ln<<<3232,256,0,stream>>>(tokens, ln2_g + l*768, ln2_b + l*768, y, nullptr, 1);
    k_gemm<<<dim3(24,26),256,0,stream>>>(y, w1, fc1_b + l*3072, nullptr, nullptr, mlp, 3232, 3072, 768, 2, 1);
    // fc2: split-K=4, atomic += into tokens
    k_gemm<<<dim3(6,26,4),256,0,stream>>>(mlp, w2, fc2_b + l*768, nullptr, tokens, nullptr,
                                          3232, 768, 3072, 0, 4);
  }

  k_ln<<<32,256,0,stream>>>(tokens, norm_g, norm_b, nullptr, cls, 101);
  k_head<<<32,256,0,stream>>>(cls, head_w, head_b, (float*)d_out);
}

// Round 5
// 2826.106 us; speedup vs baseline: 1.3672x; 1.0022x over previous
//
#include <hip/hip_runtime.h>

typedef __bf16 bf8 __attribute__((ext_vector_type(8)));
typedef float  f4  __attribute__((ext_vector_type(4)));
typedef unsigned long long uptr;

__device__ __forceinline__ void gload16(const void* g, void* l){
  __builtin_amdgcn_global_load_lds(
      (const __attribute__((address_space(1))) unsigned int*)(uptr)g,
      (__attribute__((address_space(3))) unsigned int*)(uptr)l,
      16, 0, 0);
}

// ---------------- pillar stage ----------------

__global__ __launch_bounds__(256) void k_cell(const float* __restrict__ x, int* __restrict__ cellArr,
                                              float* __restrict__ cnt, float* __restrict__ cent){
  int p = blockIdx.x*256 + threadIdx.x;            // 65536 points
  float x0 = x[p*3+0], x1 = x[p*3+1], x2 = x[p*3+2];
  float y0 = fminf(fmaxf(x0 + 1.0f, 0.0f), 1.99f);
  float y1 = fminf(fmaxf(x2 + 1.0f, 0.0f), 1.99f);
  int i0 = (int)floorf(y0 / 0.2f);
  int i1 = (int)floorf(y1 / 0.2f);
  int b = p >> 11;
  int cell = b*100 + i0*10 + i1;
  cellArr[p] = cell;
  atomicAdd(&cnt[cell], 1.0f);
  atomicAdd(&cent[cell*3+0], x1);
  atomicAdd(&cent[cell*3+1], x0);
  atomicAdd(&cent[cell*3+2], x2);
}

// counting-sort scan: base = exclusive prefix of cnt; wptr = copy of base
__global__ __launch_bounds__(256) void k_scan(const float* __restrict__ cnt,
                                              int* __restrict__ base, int* __restrict__ wptr){
  __shared__ int a[256];
  int tid = threadIdx.x;
  int start = tid*13, end = start+13; if (end > 3200) end = 3200;
  int local = 0;
  for (int i = start; i < end; i++) local += (int)cnt[i];
  a[tid] = local;
  __syncthreads();
  for (int off = 1; off < 256; off <<= 1){
    int t = (tid >= off) ? a[tid - off] : 0;
    __syncthreads();
    a[tid] += t;
    __syncthreads();
  }
  int run = a[tid] - local;
  for (int i = start; i < end; i++){
    base[i] = run; wptr[i] = run;
    run += (int)cnt[i];
  }
}

__global__ __launch_bounds__(256) void k_scatter(const int* __restrict__ cellArr,
                                                 int* __restrict__ wptr, int* __restrict__ order){
  int p = blockIdx.x*256 + threadIdx.x;
  int c = cellArr[p];
  int pos = atomicAdd(&wptr[c], 1);
  order[pos] = p;
}

__global__ __launch_bounds__(256) void k_pointmlp(const float* __restrict__ x,
    const float* __restrict__ W1, const float* __restrict__ W2, const float* __restrict__ W3,
    const float* __restrict__ cent, const float* __restrict__ cnt, const int* __restrict__ cellArr,
    const int* __restrict__ order, int* __restrict__ cellSlot, __bf16* __restrict__ A2){
  __shared__ float w1s[6*32];
  __shared__ float w2s[32*64];
  __shared__ float w3s[64*128];
  int tid = threadIdx.x;
  for (int i = tid; i < 192;  i += 256) w1s[i] = W1[i];
  for (int i = tid; i < 2048; i += 256) w2s[i] = W2[i];
  for (int i = tid; i < 8192; i += 256) w3s[i] = W3[i];
  __syncthreads();
  int s = blockIdx.x*256 + tid;                 // sorted slot
  int p = order[s];
  int cell = cellArr[p];
  cellSlot[s] = cell;
  float pf0 = x[p*3+1], pf1 = x[p*3+0], pf2 = x[p*3+2];
  float cc = fmaxf(cnt[cell], 1.0f);
  float a[6] = {pf0, pf1, pf2,
                pf0 - cent[cell*3+0]/cc, pf1 - cent[cell*3+1]/cc, pf2 - cent[cell*3+2]/cc};
  float h1[32];
  #pragma unroll
  for (int f = 0; f < 32; f++){
    float t = 0.f;
    #pragma unroll
    for (int i = 0; i < 6; i++) t += a[i]*w1s[i*32+f];
    h1[f] = fmaxf(t, 0.f);
  }
  float h2[64];
  #pragma unroll
  for (int f = 0; f < 64; f++){
    float t = 0.f;
    #pragma unroll
    for (int i = 0; i < 32; i++) t += h1[i]*w2s[i*64+f];
    h2[f] = fmaxf(t, 0.f);
  }
  for (int f0 = 0; f0 < 128; f0 += 8){
    __bf16 tmp[8];
    #pragma unroll
    for (int j = 0; j < 8; j++){
      float t = 0.f;
      #pragma unroll
      for (int i = 0; i < 64; i++) t += h2[i]*w3s[i*128+f0+j];
      tmp[j] = (__bf16)fmaxf(t, 0.f);
    }
    *reinterpret_cast<uint4*>(&A2[(size_t)s*256 + f0]) = *reinterpret_cast<uint4*>(tmp);
  }
}

__global__ __launch_bounds__(128) void k_poolh(const __bf16* __restrict__ A2,
    const int* __restrict__ base, const float* __restrict__ cnt, float* __restrict__ pooled){
  int c = blockIdx.x, f = threadIdx.x;
  int b0 = base[c], n = (int)cnt[c];
  float v = 0.f;
  for (int k = 0; k < n; k++) v = fmaxf(v, (float)A2[(size_t)(b0+k)*256 + f]);
  pooled[c*128 + f] = v;
}

__global__ __launch_bounds__(256) void k_fill(const float* __restrict__ pooled,
    const int* __restrict__ cellSlot, __bf16* __restrict__ A2){
  int idx = blockIdx.x*256 + threadIdx.x;       // 65536*16
  int s = idx >> 4, f0 = (idx & 15) << 3;
  int cell = cellSlot[s];
  const float* pp = &pooled[cell*128 + f0];
  __bf16 tmp[8];
  #pragma unroll
  for (int j = 0; j < 8; j++) tmp[j] = (__bf16)pp[j];
  *reinterpret_cast<uint4*>(&A2[(size_t)s*256 + 128 + f0]) = *reinterpret_cast<uint4*>(tmp);
}

// one block per cell, plain store (single dispatch covers full slot range)
__global__ __launch_bounds__(256) void k_pillarpool(const __bf16* __restrict__ h2c,
    const int* __restrict__ base, const float* __restrict__ cnt, float* __restrict__ pillar){
  int c = blockIdx.x, tid = threadIdx.x;
  int b0 = base[c], n = (int)cnt[c];
  if (n == 0) return;                    // pillar stays 0 from memset
  for (int f = tid; f < 768; f += 256){
    float v = 0.f;
    for (int s = b0; s < b0 + n; s++) v = fmaxf(v, (float)h2c[(size_t)s*768 + f]);
    pillar[(size_t)c*768 + f] = v;
  }
}

__global__ void k_assemble(const float* __restrict__ pillar,
    const float* __restrict__ bn_g, const float* __restrict__ bn_b,
    const float* __restrict__ bn_mean, const float* __restrict__ bn_var,
    const float* __restrict__ cls_t, const float* __restrict__ pos,
    float* __restrict__ tokens){
  int idx = blockIdx.x*256 + threadIdx.x;          // 3232*768
  int m = idx / 768, d = idx % 768;
  int b = m / 101, t = m % 101;
  float v;
  if (t == 0) v = cls_t[d];
  else {
    int s = t - 1;
    float pv = pillar[((size_t)b*100 + s)*768 + d];
    float inv = bn_g[s]*rsqrtf(bn_var[s] + 1e-5f);
    v = (pv - bn_mean[s])*inv + bn_b[s];
  }
  tokens[idx] = v + pos[t*768 + d];
}

// ---------------- weight transpose-convert ----------------

__global__ __launch_bounds__(256) void k_transpose(const float* __restrict__ W, __bf16* __restrict__ Wt,
                                                   int K, int N){
  __shared__ float t[32][33];
  int n0 = blockIdx.x*32, k0 = blockIdx.y*32;
  int tx = threadIdx.x & 31, ty = threadIdx.x >> 5;
  #pragma unroll
  for (int i = 0; i < 32; i += 8){
    int k = k0 + ty + i, n = n0 + tx;
    t[ty+i][tx] = (k < K && n < N) ? W[(size_t)k*N + n] : 0.f;
  }
  __syncthreads();
  #pragma unroll
  for (int i = 0; i < 32; i += 8){
    int n = n0 + ty + i, k = k0 + tx;
    if (n < N && k < K) Wt[(size_t)n*K + k] = (__bf16)t[tx][ty+i];
  }
}

// all 12 layers in one dispatch: grid (1728, 12).
// [128 k x 32 n] tiles: float4 reads, uint4 writes (256B contiguous per 16 lanes).
// LDS tile t[32 n][136 k-elems] with the 16B slot index XOR-swizzled by
// ((n>>1)&7): write banks spread to 16x2-addr (2-way = free), reads are a
// uniform swizzled sweep of each row. Same involution on both sides.
__global__ __launch_bounds__(256) void k_transpose_all(
    const float* __restrict__ qw, const float* __restrict__ pw,
    const float* __restrict__ f1, const float* __restrict__ f2,
    __bf16* __restrict__ wq, __bf16* __restrict__ wp,
    __bf16* __restrict__ w1, __bf16* __restrict__ w2){
  int id = blockIdx.x;
  size_t l = blockIdx.y;
  const float* W; __bf16* Wt; int K, N, kx, nx;
  if (id < 432){               W=qw+l*768*2304; Wt=wq+l*768*2304; K=768;  N=2304; kx=id%6;  nx=id/6; }
  else if (id < 576){ id-=432; W=pw+l*768*768;  Wt=wp+l*768*768;  K=768;  N=768;  kx=id%6;  nx=id/6; }
  else if (id < 1152){ id-=576;  W=f1+l*768*3072; Wt=w1+l*768*3072; K=768;  N=3072; kx=id%6;  nx=id/6; }
  else {               id-=1152; W=f2+l*3072*768; Wt=w2+l*3072*768; K=3072; N=768;  kx=id%24; nx=id/24; }
  __shared__ __bf16 t[32*136];
  int k0 = kx*128, n0 = nx*32;
  int tid = threadIdx.x;
  int kr = tid >> 3, nc = (tid & 7)*4;
  #pragma unroll
  for (int i = 0; i < 4; i++){
    int k = kr + i*32;
    float4 v = *reinterpret_cast<const float4*>(&W[(size_t)(k0+k)*N + n0 + nc]);
    float vv[4] = {v.x, v.y, v.z, v.w};
    #pragma unroll
    for (int jj = 0; jj < 4; jj++){
      int n = nc + jj;
      int slot = (k >> 3) ^ ((n >> 1) & 7);
      t[n*136 + slot*8 + (k & 7)] = (__bf16)vv[jj];
    }
  }
  __syncthreads();
  int nr = tid >> 4, sl = tid & 15;
  #pragma unroll
  for (int j = 0; j < 2; j++){
    int n = j*16 + nr;
    int slot = sl ^ ((n >> 1) & 7);
    *reinterpret_cast<uint4*>(&Wt[(size_t)(n0+n)*K + k0 + sl*8]) =
        *reinterpret_cast<uint4*>(&t[n*136 + slot*8]);
  }
}

// ---------------- bf16 MFMA GEMM, BK=64, XOR-swizzled LDS ----------------
// C[M][N] = A[M][K] @ Bt[N][K]^T ; act: 0 none, 1 relu, 2 gelu(exact)

__global__ __launch_bounds__(256) void k_gemm(const __bf16* __restrict__ A, const __bf16* __restrict__ Bt,
    const float* __restrict__ bias, const float* __restrict__ res,
    float* __restrict__ outF, __bf16* __restrict__ outB,
    int M, int N, int K, int act, int splitK){
  __shared__ alignas(16) __bf16 As[128*64];
  __shared__ alignas(16) __bf16 Bs[128*64];
  int tid  = threadIdx.x;
  int m0 = blockIdx.y*128, n0 = blockIdx.x*128;
  int z = blockIdx.z;
  int kLen = K / splitK, k0 = z*kLen;
  int wave = tid >> 6, lane = tid & 63;
  int wm = (wave >> 1)*64, wn = (wave & 1)*64;
  int r16 = lane & 15, q = lane >> 4;
  int srow = tid >> 3;           // staging row 0..31 (base)
  int sslot = tid & 7;           // staging 16B slot within 64-elem row
  int slotX[2];
  #pragma unroll
  for (int kk = 0; kk < 2; kk++) slotX[kk] = ((kk*4 + q) ^ (r16 & 7)) * 8;
  f4 acc[4][4];
  #pragma unroll
  for (int i = 0; i < 4; i++)
    #pragma unroll
    for (int j = 0; j < 4; j++) acc[i][j] = (f4){0.f,0.f,0.f,0.f};

  for (int kt = k0; kt < k0 + kLen; kt += 64){
    #pragma unroll
    for (int rr = 0; rr < 4; rr++){
      int row = rr*32 + srow;
      int scol = kt + ((sslot ^ (row & 7)) * 8);
      int gm = m0 + row; if (gm >= M) gm = M - 1;
      gload16(A  + (size_t)gm*K + scol, (char*)As + rr*4096 + tid*16);
      int gn = n0 + row;
      gload16(Bt + (size_t)gn*K + scol, (char*)Bs + rr*4096 + tid*16);
    }
    __syncthreads();
    #pragma unroll
    for (int kk = 0; kk < 2; kk++){
      bf8 af[4], bq[4];
      #pragma unroll
      for (int i = 0; i < 4; i++) af[i] = *reinterpret_cast<const bf8*>(&As[(wm + i*16 + r16)*64 + slotX[kk]]);
      #pragma unroll
      for (int j = 0; j < 4; j++) bq[j] = *reinterpret_cast<const bf8*>(&Bs[(wn + j*16 + r16)*64 + slotX[kk]]);
      #pragma unroll
      for (int i = 0; i < 4; i++)
        #pragma unroll
        for (int j = 0; j < 4; j++)
          acc[i][j] = __builtin_amdgcn_mfma_f32_16x16x32_bf16(af[i], bq[j], acc[i][j], 0, 0, 0);
    }
    __syncthreads();
  }

  #pragma unroll
  for (int i = 0; i < 4; i++){
    #pragma unroll
    for (int j = 0; j < 4; j++){
      int nn = n0 + wn + j*16 + r16;
      float bv = (bias && z == 0) ? bias[nn] : 0.f;
      #pragma unroll
      for (int r = 0; r < 4; r++){
        int m = m0 + wm + i*16 + q*4 + r;
        if (m >= M) continue;
        float v = acc[i][j][r] + bv;
        if (splitK > 1){
          atomicAdd(&outF[(size_t)m*N + nn], v);
        } else {
          if (act == 1) v = fmaxf(v, 0.f);
          else if (act == 2) v = 0.5f*v*(1.f + erff(v*0.70710678118654752f));
          if (outB){
            outB[(size_t)m*N + nn] = (__bf16)v;
          } else {
            float rv = res ? res[(size_t)m*N + nn] : 0.f;
            outF[(size_t)m*N + nn] = rv + v;
          }
        }
      }
    }
  }
}

// ---------------- layernorm (row = 768) ----------------

__global__ __launch_bounds__(256) void k_ln(const float* __restrict__ in, const float* __restrict__ g,
    const float* __restrict__ bta, __bf16* __restrict__ outB, float* __restrict__ outF, int rowMul){
  int orow = blockIdx.x;
  const float* xr = in + (size_t)orow*rowMul*768;
  int tid = threadIdx.x;
  float v0 = xr[tid], v1 = xr[tid+256], v2 = xr[tid+512];
  float s = v0+v1+v2, s2 = v0*v0 + v1*v1 + v2*v2;
  #pragma unroll
  for (int off = 32; off > 0; off >>= 1){ s += __shfl_xor(s, off); s2 += __shfl_xor(s2, off); }
  __shared__ float rs[4], rq[4];
  int w = tid >> 6;
  if ((tid & 63) == 0){ rs[w] = s; rq[w] = s2; }
  __syncthreads();
  s = rs[0]+rs[1]+rs[2]+rs[3]; s2 = rq[0]+rq[1]+rq[2]+rq[3];
  float mean = s*(1.f/768.f);
  float var  = s2*(1.f/768.f) - mean*mean;
  float rstd = rsqrtf(var + 1e-5f);
  size_t ob = (size_t)orow*768;
  float y0 = (v0-mean)*rstd*g[tid]     + bta[tid];
  float y1 = (v1-mean)*rstd*g[tid+256] + bta[tid+256];
  float y2 = (v2-mean)*rstd*g[tid+512] + bta[tid+512];
  if (outB){ outB[ob+tid]=(__bf16)y0; outB[ob+tid+256]=(__bf16)y1; outB[ob+tid+512]=(__bf16)y2; }
  else     { outF[ob+tid]=y0;         outF[ob+tid+256]=y1;         outF[ob+tid+512]=y2; }
}

// ---------------- MFMA attention: one block per (b,h,half), 64 q-rows/block ----------------

#define PSS 136   // Ps row stride (elements)
#define VTS 136   // Vt row stride (elements)

__global__ __launch_bounds__(256, 3) void k_attn(const __bf16* __restrict__ qkvB, __bf16* __restrict__ o){
  __shared__ alignas(16) __bf16 smem[64*VTS + 64*PSS];
  __bf16* Vt = smem;             // [64][VTS] : Vt[d][t]
  __bf16* Ps = smem + 64*VTS;    // [64][PSS] : local q-rows
  int bh = blockIdx.x >> 1, half = blockIdx.x & 1;
  int b = bh / 12, h = bh % 12;
  int tid = threadIdx.x;
  const __bf16* basep = qkvB + (size_t)(b*101)*2304 + h*64;

  // stage V transposed: 16B coalesced global loads, bank-staggered scalar LDS writes
  #pragma unroll
  for (int it = 0; it < 4; it++){
    int c = tid + it*256;          // [0,1024): 128 t-rows x 8 d-chunks
    int t = c >> 3, d0 = c & 7;
    bf8 v;
    if (t < 101){
      v = *reinterpret_cast<const bf8*>(&basep[(size_t)t*2304 + 1536 + d0*8]);
    } else {
      #pragma unroll
      for (int j = 0; j < 8; j++) v[j] = (__bf16)0.f;
    }
    #pragma unroll
    for (int j = 0; j < 8; j++){
      int jj = (j + d0) & 7;
      Vt[(d0*8 + jj)*VTS + t] = v[jj];
    }
  }

  int wave = tid >> 6, lane = tid & 63;
  int r16 = lane & 15, q = lane >> 4;
  int m0 = half*64 + wave*16;      // global q-row tile base

  // QK^T: direct global fragment loads, no LDS, no barrier
  f4 sacc[7];
  #pragma unroll
  for (int j = 0; j < 7; j++) sacc[j] = (f4){0.f,0.f,0.f,0.f};
  #pragma unroll
  for (int kt = 0; kt < 64; kt += 32){
    int row = m0 + r16; if (row > 100) row = 100;
    bf8 aq = *reinterpret_cast<const bf8*>(&basep[(size_t)row*2304 + kt + q*8]);
    #pragma unroll
    for (int j = 0; j < 7; j++){
      int krow = j*16 + r16; if (krow > 100) krow = 100;
      bf8 kf = *reinterpret_cast<const bf8*>(&basep[(size_t)krow*2304 + 768 + kt + q*8]);
      sacc[j] = __builtin_amdgcn_mfma_f32_16x16x32_bf16(aq, kf, sacc[j], 0, 0, 0);
    }
  }

  // softmax + write P to LDS (local rows)
  #pragma unroll
  for (int r = 0; r < 4; r++){
    float s[7];
    #pragma unroll
    for (int j = 0; j < 7; j++){
      s[j] = sacc[j][r] * 0.125f;
      if (j == 6 && r16 >= 5) s[j] = -1e30f;
    }
    float mx = s[0];
    #pragma unroll
    for (int j = 1; j < 7; j++) mx = fmaxf(mx, s[j]);
    #pragma unroll
    for (int off2 = 1; off2 < 16; off2 <<= 1) mx = fmaxf(mx, __shfl_xor(mx, off2));
    float p[7], sum = 0.f;
    #pragma unroll
    for (int j = 0; j < 7; j++){ p[j] = __expf(s[j] - mx); sum += p[j]; }
    #pragma unroll
    for (int off2 = 1; off2 < 16; off2 <<= 1) sum += __shfl_xor(sum, off2);
    float inv = 1.f / sum;
    int lr = wave*16 + q*4 + r;
    #pragma unroll
    for (int j = 0; j < 7; j++) Ps[lr*PSS + j*16 + r16] = (__bf16)(p[j]*inv);
    Ps[lr*PSS + 112 + r16] = (__bf16)0.f;
  }
  __syncthreads();

  // PV: A from Ps, B from Vt — single ds_read_b128 per fragment
  f4 oacc[4];
  #pragma unroll
  for (int n = 0; n < 4; n++) oacc[n] = (f4){0.f,0.f,0.f,0.f};
  #pragma unroll
  for (int kt = 0; kt < 128; kt += 32){
    bf8 af = *reinterpret_cast<const bf8*>(&Ps[(wave*16 + r16)*PSS + kt + q*8]);
    #pragma unroll
    for (int n = 0; n < 4; n++){
      bf8 bq = *reinterpret_cast<const bf8*>(&Vt[(n*16 + r16)*VTS + kt + q*8]);
      oacc[n] = __builtin_amdgcn_mfma_f32_16x16x32_bf16(af, bq, oacc[n], 0, 0, 0);
    }
  }

  #pragma unroll
  for (int n = 0; n < 4; n++){
    #pragma unroll
    for (int r = 0; r < 4; r++){
      int t = m0 + q*4 + r;
      if (t < 101)
        o[((size_t)(b*101 + t))*768 + h*64 + n*16 + r16] = (__bf16)oacc[n][r];
    }
  }
}

__global__ __launch_bounds__(256) void k_head(const float* __restrict__ cls, const float* __restrict__ hw,
                       const float* __restrict__ hb, float* __restrict__ out){
  int b = blockIdx.x;
  int tid = threadIdx.x;
  int c = tid % 40, s = tid / 40;   // s in 0..6 (tid>=240 idle)
  __shared__ float part[6][40];
  if (s < 6){
    float acc = 0.f;
    for (int k = s*128; k < s*128 + 128; k++) acc += cls[b*768 + k]*hw[k*40 + c];
    part[s][c] = acc;
  }
  __syncthreads();
  if (tid < 40){
    float v = hb[tid];
    #pragma unroll
    for (int i = 0; i < 6; i++) v += part[i][tid];
    out[b*40 + tid] = v;
  }
}

// ---------------- launch ----------------

extern "C" void kernel_launch(void* const* d_in, const int* in_sizes, int n_in,
                              void* d_out, int out_size, void* d_ws, size_t ws_size,
                              hipStream_t stream){
  const float* x       = (const float*)d_in[0];
  const float* W1      = (const float*)d_in[1];
  const float* W2      = (const float*)d_in[2];
  const float* W3      = (const float*)d_in[3];
  const float* Wa      = (const float*)d_in[4];
  const float* bn_g    = (const float*)d_in[5];
  const float* bn_b    = (const float*)d_in[6];
  const float* bn_mean = (const float*)d_in[7];
  const float* bn_var  = (const float*)d_in[8];
  const float* cls_t   = (const float*)d_in[9];
  const float* pos     = (const float*)d_in[10];
  const float* ln1_g   = (const float*)d_in[11];
  const float* ln1_b   = (const float*)d_in[12];
  const float* qkv_w   = (const float*)d_in[13];
  const float* proj_w  = (const float*)d_in[14];
  const float* proj_b  = (const float*)d_in[15];
  const float* ln2_g   = (const float*)d_in[16];
  const float* ln2_b   = (const float*)d_in[17];
  const float* fc1_w   = (const float*)d_in[18];
  const float* fc1_b   = (const float*)d_in[19];
  const float* fc2_w   = (const float*)d_in[20];
  const float* fc2_b   = (const float*)d_in[21];
  const float* norm_g  = (const float*)d_in[22];
  const float* norm_b  = (const float*)d_in[23];
  const float* head_w  = (const float*)d_in[24];
  const float* head_b  = (const float*)d_in[25];

  char* ws = (char*)d_ws;
  size_t off = 0;
  auto alloc = [&](size_t bytes)->void*{ void* p = ws + off; off += (bytes + 255) & ~(size_t)255; return p; };
  // --- persistent region ---
  float* cnt     = (float*)alloc(3200*4);
  float* cent    = (float*)alloc(3200*3*4);
  float* pillar  = (float*)alloc((size_t)3200*768*4);
  size_t zbytes  = (size_t)((char*)pillar - (char*)cnt) + (size_t)3200*768*4;
  int*   base    = (int*)  alloc(3200*4);
  int*   wptr    = (int*)  alloc(3200*4);
  int*   order   = (int*)  alloc((size_t)65536*4);
  int*   cellSlot= (int*)  alloc((size_t)65536*4);
  int*   cellArr = (int*)  alloc((size_t)65536*4);
  float* pooled  = (float*)alloc((size_t)3200*128*4);
  float* tokens  = (float*)alloc((size_t)3232*768*4);
  float* cls     = (float*)alloc((size_t)32*768*4);
  __bf16* wWa    = (__bf16*)alloc((size_t)768*256*2);
  // all-layer transposed weights (persistent through the transformer loop)
  __bf16* wq12   = (__bf16*)alloc((size_t)12*768*2304*2);
  __bf16* wp12   = (__bf16*)alloc((size_t)12*768*768*2);
  __bf16* w112   = (__bf16*)alloc((size_t)12*768*3072*2);
  __bf16* w212   = (__bf16*)alloc((size_t)12*3072*768*2);
  // --- overlaid region R ---
  size_t offR = off;
  __bf16* A2  = (__bf16*)alloc((size_t)65536*256*2);
  __bf16* h2c = (__bf16*)alloc((size_t)65536*768*2);
  size_t endPillarPhase = off;
  off = offR;
  __bf16* y    = (__bf16*)alloc((size_t)3232*768*2);
  __bf16* qkvB = (__bf16*)alloc((size_t)3232*2304*2);
  __bf16* o    = (__bf16*)alloc((size_t)3232*768*2);
  __bf16* mlp  = (__bf16*)alloc((size_t)3232*3072*2);
  if (off < endPillarPhase) off = endPillarPhase;
  (void)ws_size; (void)in_sizes; (void)n_in; (void)out_size;

  hipMemsetAsync(cnt, 0, zbytes, stream);

  // all weight transposes upfront (one dispatch for 12 layers)
  k_transpose_all<<<dim3(1728,12),256,0,stream>>>(qkv_w, proj_w, fc1_w, fc2_w, wq12, wp12, w112, w212);
  k_transpose<<<dim3(24,8),256,0,stream>>>(Wa, wWa, 256, 768);

  // pillar feature stage
  k_cell<<<256,256,0,stream>>>(x, cellArr, cnt, cent);
  k_scan<<<1,256,0,stream>>>(cnt, base, wptr);
  k_scatter<<<256,256,0,stream>>>(cellArr, wptr, order);
  k_pointmlp<<<256,256,0,stream>>>(x, W1, W2, W3, cent, cnt, cellArr, order, cellSlot, A2);
  k_poolh<<<3200,128,0,stream>>>(A2, base, cnt, pooled);
  k_fill<<<4096,256,0,stream>>>(pooled, cellSlot, A2);
  k_gemm<<<dim3(6,512),256,0,stream>>>(A2, wWa, nullptr, nullptr, nullptr, h2c, 65536, 768, 256, 1, 1);
  k_pillarpool<<<3200,256,0,stream>>>(h2c, base, cnt, pillar);
  k_assemble<<<9696,256,0,stream>>>(pillar, bn_g, bn_b, bn_mean, bn_var, cls_t, pos, tokens);

  // transformer
  for (int l = 0; l < 12; l++){
    __bf16* wq = wq12 + (size_t)l*768*2304;
    __bf16* wp = wp12 + (size_t)l*768*768;
    __bf16* w1 = w112 + (size_t)l*768*3072;
    __bf16* w2 = w212 + (size_t)l*3072*768;
    k_ln<<<3232,256,0,stream>>>(tokens, ln1_g + l*768, ln1_b + l*768, y, nullptr, 1);
    k_gemm<<<dim3(18,26),256,0,stream>>>(y, wq, nullptr, nullptr, nullptr, qkvB, 3232, 2304, 768, 0, 1);
    k_attn<<<768,256,0,stream>>>(qkvB, o);
    // proj: split-K=4, atomic += into tokens (tokens already holds residual h)
    k_gemm<<<dim3(6,26,4),256,0,stream>>>(o, wp, proj_b + l*768, nullptr, tokens, nullptr,
                                          3232, 768, 768, 0, 4);
    k_ln<<<3232,256,0,stream>>>(tokens, ln2_g + l*768, ln2_b + l*768, y, nullptr, 1);
    k_gemm<<<dim3(24,26),256,0,stream>>>(y, w1, fc1_b + l*3072, nullptr, nullptr, mlp, 3232, 3072, 768, 2, 1);
    // fc2: split-K=4, atomic += into tokens
    k_gemm<<<dim3(6,26,4),256,0,stream>>>(mlp, w2, fc2_b + l*768, nullptr, tokens, nullptr,
                                          3232, 768, 3072, 0, 4);
  }

  k_ln<<<32,256,0,stream>>>(tokens, norm_g, norm_b, nullptr, cls, 101);
  k_head<<<32,256,0,stream>>>(cls, head_w, head_b, (float*)d_out);
}